// Round 8
// baseline (404.567 us; speedup 1.0000x reference)
//
#include <hip/hip_runtime.h>
#include <cstddef>
#include <cstdint>
#include <math.h>

// Problem constants
#define LSEQ   4096
#define BATCH  4
#define TTOK   (LSEQ * BATCH)      // 16384 rows
#define QCH    128                 // scan chunk length
#define NCH    (LSEQ / QCH)        // 32 chunks per sequence
#define NPAD   2304                // in_proj N padded to 18*128
// D_MODEL=512, D_INNER=1024, CONV_DIM=1152, NHEADS=16, HEADDIM=64, D_STATE=64
// g1out layout (ld 2304): [0,1024) z | [1024,2176) xBC | [2176,2192) dt_raw | pad
// Scan runs in reversed-time index r = 4095 - l (forward scan in r).
// rms scale KEPT (rounds 4-6 lesson: LN-invariance fails for tiny-norm rows
// because the rms eps floors them). LN folded into MLP1 (exact algebra).
// in_proj GEMM uses BK=32 (64KB LDS -> 2 blocks/CU co-resident: fills the
// barrier/staging stalls that capped the 128KB BK=64 variant at 22% MfmaUtil).

typedef __attribute__((ext_vector_type(8))) short short8;
typedef __attribute__((ext_vector_type(8))) unsigned short ushortx8;
typedef __attribute__((ext_vector_type(4))) float floatx4;

// ---- bf16 helpers (manual, RNE) ----
__device__ __forceinline__ float bf2f(ushort u) {
    union { unsigned int i; float f; } v; v.i = ((unsigned int)u) << 16; return v.f;
}
__device__ __forceinline__ ushort f2bf(float f) {
    union { float f; unsigned int i; } v; v.f = f;
    unsigned int r = v.i + 0x7fffu + ((v.i >> 16) & 1u);
    return (ushort)(r >> 16);
}
__device__ __forceinline__ float silu_f(float a) {
    return a / (1.f + __expf(-a));
}

__device__ __forceinline__ void storev(float* p, float v)  { *p = v; }
__device__ __forceinline__ void storev(ushort* p, float v) { *p = f2bf(v); }

// 16B-chunk XOR swizzles for LDS tiles (conflict-free b128 frag reads)
__device__ __forceinline__ int sw64i(int row, int col) {
    return row * 64 + ((((col >> 3) ^ row) & 7) << 3) + (col & 7);
}
__device__ __forceinline__ int sw128i(int row, int col) {
    return row * 128 + ((((col >> 3) ^ row) & 15) << 3) + (col & 7);
}

// async 16B global -> LDS (wave-uniform LDS base + lane*16)
__device__ __forceinline__ void gload_lds16(const ushort* g, short* l) {
    __builtin_amdgcn_global_load_lds(
        (const __attribute__((address_space(1))) void*)g,
        (__attribute__((address_space(3))) void*)l, 16, 0, 0);
}

// raw waits / barriers (NO __syncthreads in the GEMM: it would drain vmcnt)
__device__ __forceinline__ void vmwait4() { asm volatile("s_waitcnt vmcnt(4)" ::: "memory"); }
__device__ __forceinline__ void vmwait3() { asm volatile("s_waitcnt vmcnt(3)" ::: "memory"); }
__device__ __forceinline__ void vmwait2() { asm volatile("s_waitcnt vmcnt(2)" ::: "memory"); }
__device__ __forceinline__ void vmwait0() { asm volatile("s_waitcnt vmcnt(0)" ::: "memory"); }
__device__ __forceinline__ void wgbar() {
    __builtin_amdgcn_sched_barrier(0);
    __builtin_amdgcn_s_barrier();
    __builtin_amdgcn_sched_barrier(0);
}

// ---------------------------------------------------------------------------
// 256x{256,128} 8-phase bf16 MFMA GEMM: C[M,N] = epi(A[M,K] @ W[N,K]^T + bias)
// EPI: 0 none | 1 silu
//      2 rms row-scale: v *= rsqrt(aux[row]/1024 + eps)
//      5 fused-LayerNorm affine + silu:
//        v = silu(acc*inv - mi*aux3[col] + bias[col]); mi=aux[row], inv=aux2[row]
// BK: 64 (128KB LDS, 1 block/CU) or 32 (64KB LDS, 2 blocks/CU co-residency).
// Steady-state counted wait keeps ALD+BLD half-tiles in flight (never 0).
// ---------------------------------------------------------------------------
template<int EPI, typename OutT, int BN, int BK>
__global__ __launch_bounds__(512, 2)
void gemm256(const ushort* __restrict__ A, const ushort* __restrict__ W,
             const float* __restrict__ bias, const float* __restrict__ aux,
             const float* __restrict__ aux2, const float* __restrict__ aux3,
             OutT* __restrict__ C, int M, int N, int K)
{
    constexpr int ABUF  = 128 * BK;             // shorts per A half-region
    constexpr int BHALF = (BN / 2) * BK;        // shorts per B half-region
    constexpr int TPR   = BK / 8;               // staging threads (16B chunks) per row
    constexpr int ALD   = ABUF / 4096;          // 16B gloads/thread per A half
    constexpr int BLD   = BHALF / 4096;         // 16B gloads/thread per B half
    constexpr int KCH   = BK / 32;              // K=32 MFMA chunks per tile
    constexpr int NFH   = (BN == 256) ? 2 : 1;  // B frags per N-half per wave
    constexpr int NKEEP = ALD + BLD;            // in-flight halves at steady wait
    __shared__ __align__(16) short As[4 * ABUF];   // 2 buf x 2 half
    __shared__ __align__(16) short Bs[4 * BHALF];  // 2 buf x 2 half

    const int tid = threadIdx.x;
    const int w = tid >> 6, lane = tid & 63;
    const int lm = lane & 15, quad = lane >> 4;
    const int wm = w & 1, wn = w >> 1;

    // row -> chunk-XOR swizzle (involution; applied on global source AND reads)
    auto swzf = [](int r) -> int {
        if constexpr (BK == 64) return r & 7;
        else                    return (r & 3) ^ ((r >> 2) & 3);
    };

    // XCD-chunked bijective swizzle (nwg % 8 == 0 for all our grids)
    const int nwg = gridDim.x;
    const int chunk = nwg >> 3;
    const int bid = blockIdx.x;
    const int vid = (bid & 7) * chunk + (bid >> 3);
    const int NX = N / BN;
    const int bx = vid % NX, by = vid / NX;
    const int m0 = by * 256, n0 = bx * BN;
    const int NT = K / BK;                      // K-tiles (>= 8 here)

    const int srow = tid / TPR;
    const int scol = (((tid % TPR) ^ swzf(srow)) & (TPR - 1)) * 8;
    const ushort* ga = A + (size_t)(m0 + srow) * K + scol;
    const ushort* gb = W + (size_t)(n0 + srow) * K + scol;
    short* lA = As + w * 512;
    short* lB = Bs + w * 512;

    auto STAGE_A = [&](int bf, int h, int kt) {
        const ushort* g = ga + (size_t)(h * 128) * K + kt * BK;
        short* l = lA + bf * 2 * ABUF + h * ABUF;
#pragma unroll
        for (int i = 0; i < ALD; ++i)
            gload_lds16(g + (size_t)(i * (4096 / BK)) * K, l + i * 4096);
    };
    auto STAGE_B = [&](int bf, int h, int kt) {
        const ushort* g = gb + (size_t)(h * (BN / 2)) * K + kt * BK;
        short* l = lB + bf * 2 * BHALF + h * BHALF;
#pragma unroll
        for (int i = 0; i < BLD; ++i)
            gload_lds16(g + (size_t)(i * (4096 / BK)) * K, l + i * 4096);
    };

    int aRow[4], bRow[NFH], kch[KCH];
#pragma unroll
    for (int i = 0; i < 4; ++i) aRow[i] = ((i * 2 + wm) * 16 + lm) * BK;
#pragma unroll
    for (int j = 0; j < NFH; ++j) bRow[j] = ((j * 4 + wn) * 16 + lm) * BK;
#pragma unroll
    for (int ks = 0; ks < KCH; ++ks)
        kch[ks] = (((ks * 4 + quad) ^ swzf(lm)) & (TPR - 1)) * 8;

    floatx4 acc[8][2 * NFH];
#pragma unroll
    for (int i = 0; i < 8; ++i)
#pragma unroll
        for (int j = 0; j < 2 * NFH; ++j) acc[i][j] = (floatx4){0.f, 0.f, 0.f, 0.f};
    short8 af[4][KCH], bfr[NFH][KCH];

#define G_LOADA(bfv, MH)                                                      \
    {                                                                         \
        const short* _ba = As + (bfv) * 2 * ABUF + (MH) * ABUF;               \
        _Pragma("unroll")                                                     \
        for (int _i = 0; _i < 4; ++_i)                                        \
            _Pragma("unroll")                                                 \
            for (int _k = 0; _k < KCH; ++_k)                                  \
                af[_i][_k] = *(const short8*)(_ba + aRow[_i] + kch[_k]);      \
    }
#define G_LOADB(bfv, NH)                                                      \
    {                                                                         \
        const short* _bb = Bs + (bfv) * 2 * BHALF + (NH) * BHALF;             \
        _Pragma("unroll")                                                     \
        for (int _j = 0; _j < NFH; ++_j)                                      \
            _Pragma("unroll")                                                 \
            for (int _k = 0; _k < KCH; ++_k)                                  \
                bfr[_j][_k] = *(const short8*)(_bb + bRow[_j] + kch[_k]);     \
    }
#define G_MMA(MH, NH)                                                         \
    {                                                                         \
        __builtin_amdgcn_s_setprio(1);                                        \
        _Pragma("unroll")                                                     \
        for (int _i = 0; _i < 4; ++_i)                                        \
            _Pragma("unroll")                                                 \
            for (int _j = 0; _j < NFH; ++_j)                                  \
                _Pragma("unroll")                                             \
                for (int _k = 0; _k < KCH; ++_k)                              \
                    acc[(MH) * 4 + _i][(NH) * NFH + _j] =                     \
                        __builtin_amdgcn_mfma_f32_16x16x32_bf16(              \
                            af[_i][_k], bfr[_j][_k],                          \
                            acc[(MH) * 4 + _i][(NH) * NFH + _j], 0, 0, 0);    \
        __builtin_amdgcn_s_setprio(0);                                        \
    }
#define VMKEEP()                                                              \
    {                                                                         \
        if constexpr (NKEEP == 4) vmwait4();                                  \
        else if constexpr (NKEEP == 3) vmwait3();                             \
        else vmwait2();                                                       \
    }

    STAGE_A(0, 0, 0); STAGE_B(0, 0, 0); STAGE_B(0, 1, 0); STAGE_A(0, 1, 0);
    STAGE_A(1, 0, 1); STAGE_B(1, 1, 1);
    VMKEEP();
    wgbar();

    for (int t = 0; t < NT; ++t) {
        const int bf = t & 1;
        G_LOADA(bf, 0); G_LOADB(bf, 0);
        if (t + 1 < NT) STAGE_B(bf ^ 1, 0, t + 1);
        wgbar();
        G_MMA(0, 0);
        wgbar();
        G_LOADB(bf, 1);
        if (t + 1 < NT) STAGE_A(bf ^ 1, 1, t + 1);
        wgbar();
        G_MMA(0, 1);
        wgbar();
        G_LOADA(bf, 1);
        if (t + 2 < NT) STAGE_A(bf, 0, t + 2);
        wgbar();
        G_MMA(1, 1);
        wgbar();
        G_LOADB(bf, 0);
        if (t + 2 < NT) STAGE_B(bf, 1, t + 2);
        wgbar();
        G_MMA(1, 0);
        __builtin_amdgcn_sched_barrier(0);
        if (t + 2 < NT) { VMKEEP(); }
        else if (t + 1 < NT) vmwait0();
        wgbar();
    }
#undef G_LOADA
#undef G_LOADB
#undef G_MMA
#undef VMKEEP

    // epilogue
#pragma unroll
    for (int ii = 0; ii < 8; ++ii) {
        const int rb = m0 + (ii * 2 + wm) * 16 + quad * 4;
#pragma unroll
        for (int rr = 0; rr < 4; ++rr) {
            const int row = rb + rr;
            float inv = 1.f, mi = 0.f, scale = 1.f;
            if (EPI == 2) scale = rsqrtf(aux[row] * (1.f / 1024.f) + 1e-5f);
            if (EPI == 5) { mi = aux[row]; inv = aux2[row]; }
#pragma unroll
            for (int jj = 0; jj < 2 * NFH; ++jj) {
                const int col = n0 + (jj * 4 + wn) * 16 + lm;
                float v = acc[ii][jj][rr];
                if (EPI == 5) {
                    v = silu_f(v * inv - mi * aux3[col] + bias[col]);
                } else {
                    if (bias) v += bias[col];
                    if (EPI == 1) v = silu_f(v);
                    if (EPI == 2) v *= scale;
                }
                storev(&C[(size_t)row * N + col], v);
            }
        }
    }
}

// ---------------------------------------------------------------------------
// casts
// ---------------------------------------------------------------------------
__global__ __launch_bounds__(256)
void cast_x_k(const float4* __restrict__ in, ushort4* __restrict__ out, int n4)
{
    int i = blockIdx.x * 256 + threadIdx.x;
    if (i >= n4) return;
    float4 v = in[i];
    ushort4 o;
    o.x = f2bf(v.x); o.y = f2bf(v.y); o.z = f2bf(v.z); o.w = f2bf(v.w);
    out[i] = o;
}

// weight preps: in_proj pad, w1 fold (+ln_g fold), out_proj*rms_w, w2
__global__ __launch_bounds__(256)
void prep_weights(const float* __restrict__ ipw, const float* __restrict__ w1,
                  const float* __restrict__ wop, const float* __restrict__ w2,
                  const float* __restrict__ rw, const float* __restrict__ lng,
                  ushort* __restrict__ wip, ushort* __restrict__ w1g,
                  ushort* __restrict__ wopb, ushort* __restrict__ w2b)
{
    int i4 = (blockIdx.x * 256 + threadIdx.x) * 4;
    if (i4 < NPAD * 512) {
        int row = i4 >> 9;
        ushort4 v;
        if (row < 2192) {
            float4 s = *(const float4*)(ipw + (size_t)i4);
            v.x = f2bf(s.x); v.y = f2bf(s.y); v.z = f2bf(s.z); v.w = f2bf(s.w);
        } else { v.x = v.y = v.z = v.w = 0; }
        *(ushort4*)(wip + i4) = v;
        return;
    }
    i4 -= NPAD * 512;
    if (i4 < 1024 * 512) {
        int j = i4 >> 9, d = i4 & 511;
        float4 a = *(const float4*)(w1 + (size_t)j * 1024 + d);
        float4 b = *(const float4*)(w1 + (size_t)j * 1024 + 512 + d);
        float4 g = *(const float4*)(lng + d);
        ushort4 v;
        v.x = f2bf((a.x + b.x) * g.x); v.y = f2bf((a.y + b.y) * g.y);
        v.z = f2bf((a.z + b.z) * g.z); v.w = f2bf((a.w + b.w) * g.w);
        *(ushort4*)(w1g + i4) = v;
        return;
    }
    i4 -= 1024 * 512;
    if (i4 < 512 * 1024) {
        float4 s = *(const float4*)(wop + (size_t)i4);
        float4 g = *(const float4*)(rw + (i4 & 1023));
        ushort4 v;
        v.x = f2bf(s.x * g.x); v.y = f2bf(s.y * g.y);
        v.z = f2bf(s.z * g.z); v.w = f2bf(s.w * g.w);
        *(ushort4*)(wopb + i4) = v;
        return;
    }
    i4 -= 512 * 1024;
    if (i4 < 512 * 1024) {
        float4 s = *(const float4*)(w2 + (size_t)i4);
        ushort4 v;
        v.x = f2bf(s.x); v.y = f2bf(s.y); v.z = f2bf(s.z); v.w = f2bf(s.w);
        *(ushort4*)(w2b + i4) = v;
    }
}

// row-sums for the LN->MLP1 fold: Sg[n] = sum_k w1f[n,k]*ln_g[k],
// SB[n] = sum_k w1f[n,k]*ln_b[k] + b1[n], with w1f = w1[:, :512]+w1[:, 512:].
__global__ __launch_bounds__(256)
void prep_rowsums(const float* __restrict__ w1, const float* __restrict__ g,
                  const float* __restrict__ bb, const float* __restrict__ b1,
                  float* __restrict__ Sg, float* __restrict__ SB)
{
    const int n = blockIdx.x * 4 + (threadIdx.x >> 6);
    const int lane = threadIdx.x & 63;
    float sg = 0.f, sb = 0.f;
#pragma unroll
    for (int it = 0; it < 8; ++it) {
        int k = it * 64 + lane;
        float wv = w1[(size_t)n * 1024 + k] + w1[(size_t)n * 1024 + 512 + k];
        sg += wv * g[k];
        sb += wv * bb[k];
    }
#pragma unroll
    for (int off = 32; off > 0; off >>= 1) {
        sg += __shfl_xor(sg, off);
        sb += __shfl_xor(sb, off);
    }
    if (lane == 0) { Sg[n] = sg; SB[n] = sb + b1[n]; }
}

// ---------------------------------------------------------------------------
// LN row stats from bf16 y2 (already rms-scaled): one wave per row.
// Writes mi = mean*inv and inv = rsqrt(var+eps).
// ---------------------------------------------------------------------------
__global__ __launch_bounds__(256)
void ln_stats(const ushort* __restrict__ y2, float* __restrict__ miv,
              float* __restrict__ invv)
{
    const int w = threadIdx.x >> 6, lane = threadIdx.x & 63;
#pragma unroll
    for (int it = 0; it < 4; ++it) {
        const int row = blockIdx.x * 16 + it * 4 + w;
        ushortx8 v = *(const ushortx8*)(y2 + (size_t)row * 512 + lane * 8);
        float s = 0.f, ss = 0.f;
#pragma unroll
        for (int e = 0; e < 8; ++e) { float f = bf2f(v[e]); s += f; ss += f * f; }
#pragma unroll
        for (int off = 32; off > 0; off >>= 1) {
            s += __shfl_xor(s, off);
            ss += __shfl_xor(ss, off);
        }
        if (lane == 0) {
            float mean = s * (1.f / 512.f);
            float var  = ss * (1.f / 512.f) - mean * mean;
            float inv  = rsqrtf(var + 1e-5f);
            miv[row]  = mean * inv;
            invv[row] = inv;
        }
    }
}

// ---------------------------------------------------------------------------
// seg_scan (dt fused)
// ---------------------------------------------------------------------------
__global__ __launch_bounds__(128)
void seg_scan(const ushort* __restrict__ raw, const float* __restrict__ dt_bias,
              const float* __restrict__ A_log, float* __restrict__ dtr,
              float* __restrict__ segb, float* __restrict__ alphab,
              float* __restrict__ Pb)
{
    __shared__ float s[128];
    const int tid = threadIdx.x;
    const int c = blockIdx.x, h = blockIdx.y, b = blockIdx.z;
    const int bh = b * 16 + h;
    const int r = c * QCH + tid;
    const size_t grow = (size_t)b * LSEQ + (LSEQ - 1 - r);
    const size_t idx = (size_t)bh * LSEQ + r;

    float v = bf2f(raw[grow * NPAD + 2176 + h]) + dt_bias[h];
    float dt = (v > 20.f) ? v : log1pf(expf(v));
    float Ah = -expf(A_log[h]);
    s[tid] = dt * Ah;
    __syncthreads();
#pragma unroll
    for (int off = 1; off < 128; off <<= 1) {
        float t = (tid >= off) ? s[tid - off] : 0.f;
        __syncthreads();
        s[tid] += t;
        __syncthreads();
    }
    float seg = s[tid];
    float last = s[127];
    dtr[idx] = dt;
    segb[idx] = seg;
    alphab[idx] = __expf(last - seg) * dt;
    if (tid == 127) Pb[bh * NCH + c] = __expf(last);
}

// ---------------------------------------------------------------------------
// Anti-causal depthwise conv + silu, rolling-window.
// ---------------------------------------------------------------------------
#define CSTRIP 8
__global__ __launch_bounds__(256)
void conv_silu(const ushort* __restrict__ raw, const float* __restrict__ cw,
               const float* __restrict__ cb, ushort* __restrict__ xh,
               ushort* __restrict__ bc)
{
    const int idx = blockIdx.x * 256 + threadIdx.x;   // over (TTOK/CSTRIP)*144
    if (idx >= (TTOK / CSTRIP) * 144) return;
    const int strip = idx / 144;
    const int g = idx - strip * 144;
    const int c0 = g * 8;
    const int row0 = strip * CSTRIP;                  // global first row
    const int l0 = row0 & (LSEQ - 1);

    float wt[4][8];
    float bias[8];
#pragma unroll
    for (int e = 0; e < 8; ++e) {
        float4 a = *(const float4*)(cw + (c0 + e) * 4);
        wt[0][e] = a.w; wt[1][e] = a.z; wt[2][e] = a.y; wt[3][e] = a.x;
        bias[e] = cb[c0 + e];
    }

    float win[4][8];
    auto loadrow = [&](int l, float* dst) {
        if (l < LSEQ) {
            ushortx8 v = *(const ushortx8*)(raw + (size_t)(row0 - l0 + l) * NPAD + 1024 + c0);
#pragma unroll
            for (int e = 0; e < 8; ++e) dst[e] = bf2f(v[e]);
        } else {
#pragma unroll
            for (int e = 0; e < 8; ++e) dst[e] = 0.f;
        }
    };

    {
        const int ltop = l0 + CSTRIP - 1;
        loadrow(ltop + 1, win[(ltop + 1) & 3]);
        loadrow(ltop + 2, win[(ltop + 2) & 3]);
        loadrow(ltop + 3, win[(ltop + 3) & 3]);
    }
#pragma unroll
    for (int s = CSTRIP - 1; s >= 0; --s) {
        const int l = l0 + s;
        loadrow(l, win[l & 3]);
        ushortx8 o;
#pragma unroll
        for (int e = 0; e < 8; ++e) {
            float acc = bias[e];
#pragma unroll
            for (int j = 0; j < 4; ++j)
                acc = fmaf(wt[j][e], win[(l + j) & 3][e], acc);
            o[e] = f2bf(silu_f(acc));
        }
        const size_t row = (size_t)row0 + s;
        if (c0 < 1024) *(ushortx8*)(xh + row * 1024 + c0) = o;
        else           *(ushortx8*)(bc + row * 128 + (c0 - 1024)) = o;
    }
}

// ---------------------------------------------------------------------------
// SSD pass A: per tile (c,h,b), chunk end-state
// ---------------------------------------------------------------------------
__global__ __launch_bounds__(256)
void ssd_states(const ushort* __restrict__ xh, const ushort* __restrict__ bc,
                const float* __restrict__ alphab, float* __restrict__ sbuf)
{
    __shared__ __align__(16) ushort XT[64 * 128];
    __shared__ __align__(16) ushort BpT[64 * 128];
    const int tid = threadIdx.x;
    const int w = tid >> 6, lane = tid & 63;
    const int lm = lane & 15, quad = lane >> 4;
    const int c = blockIdx.x, h = blockIdx.y, b = blockIdx.z;
    const int bh = b * 16 + h;
    const size_t abase = (size_t)bh * LSEQ + c * QCH;

#pragma unroll
    for (int it = 0; it < 8; ++it) {
        int idx = it * 256 + tid;
        int tau = idx >> 4, e4 = (idx & 15) * 4;
        size_t grow = (size_t)b * LSEQ + (LSEQ - 1 - (c * QCH + tau));
        ushort4 xv = *(const ushort4*)(xh + grow * 1024 + h * 64 + e4);
        XT[sw128i(e4 + 0, tau)] = xv.x;
        XT[sw128i(e4 + 1, tau)] = xv.y;
        XT[sw128i(e4 + 2, tau)] = xv.z;
        XT[sw128i(e4 + 3, tau)] = xv.w;
        float al = alphab[abase + tau];
        ushort4 bv = *(const ushort4*)(bc + grow * 128 + e4);
        BpT[sw128i(e4 + 0, tau)] = f2bf(bf2f(bv.x) * al);
        BpT[sw128i(e4 + 1, tau)] = f2bf(bf2f(bv.y) * al);
        BpT[sw128i(e4 + 2, tau)] = f2bf(bf2f(bv.z) * al);
        BpT[sw128i(e4 + 3, tau)] = f2bf(bf2f(bv.w) * al);
    }
    __syncthreads();

    floatx4 L[4];
#pragma unroll
    for (int j = 0; j < 4; ++j) L[j] = (floatx4){0.f, 0.f, 0.f, 0.f};
#pragma unroll
    for (int kc = 0; kc < 4; ++kc) {
        short8 a = *(const short8*)(XT + sw128i(w * 16 + lm, kc * 32 + quad * 8));
#pragma unroll
        for (int jn = 0; jn < 4; ++jn) {
            short8 bf = *(const short8*)(BpT + sw128i(jn * 16 + lm, kc * 32 + quad * 8));
            L[jn] = __builtin_amdgcn_mfma_f32_16x16x32_bf16(a, bf, L[jn], 0, 0, 0);
        }
    }
    float* Sp = sbuf + ((size_t)bh * NCH + c) * 4096;
#pragma unroll
    for (int jn = 0; jn < 4; ++jn)
#pragma unroll
        for (int r = 0; r < 4; ++r) {
            int p = w * 16 + quad * 4 + r;
            Sp[p * 64 + jn * 16 + lm] = L[jn][r];
        }
}

// ---------------------------------------------------------------------------
// Combine: sequential over chunks in scan (r) order, prefetched; writes the
// chunk-start state h as PACKED BF16 (block-partitioned layout + barrier).
// q==0 blocks also zero the per-row ssq accumulator for the rms fusion.
// ---------------------------------------------------------------------------
__global__ __launch_bounds__(256)
void scan_combine(float* __restrict__ sbuf, const float* __restrict__ Pb,
                  float* __restrict__ ssq)
{
    const int tid = threadIdx.x;
    const int q = blockIdx.x, h = blockIdx.y, b = blockIdx.z;
    const int bh = b * 16 + h;
    if (q == 0) ssq[(size_t)bh * 256 + tid] = 0.f;
    const int off = q * 1024 + tid * 4;
    float c0 = 0.f, c1 = 0.f, c2 = 0.f, c3 = 0.f;

    float* slotbase = sbuf + (size_t)bh * NCH * 4096;
    float* sp0 = slotbase + off;
    float4 nx = *(const float4*)sp0;
    float Pn = Pb[bh * NCH];

    for (int c = 0; c < NCH; ++c) {
        float4 lv = nx;
        float P = Pn;
        if (c + 1 < NCH) {
            nx = *(const float4*)(sp0 + (size_t)(c + 1) * 4096);
            Pn = Pb[bh * NCH + c + 1];
        }
        __syncthreads();   // slot-c reads (prev iter) done before slot-c writes
        ushort* hdst = (ushort*)(slotbase + (size_t)c * 4096) + q * 2048 + tid * 4;
        ushort4 hv;
        hv.x = f2bf(c0); hv.y = f2bf(c1); hv.z = f2bf(c2); hv.w = f2bf(c3);
        *(ushort4*)hdst = hv;
        c0 = fmaf(c0, P, lv.x);
        c1 = fmaf(c1, P, lv.y);
        c2 = fmaf(c2, P, lv.z);
        c3 = fmaf(c3, P, lv.w);
    }
}

// ---------------------------------------------------------------------------
// SSD pass C: Y = [M o (C B^T)] X + diag(exp(seg)) C h_start^T, D on diag,
// z-gate fused, writes gated bf16 + atomic per-row ssq (rms fusion).
// Triangular skip with balanced bands.
// ---------------------------------------------------------------------------
__global__ __launch_bounds__(256)
void ssd_y(const ushort* __restrict__ xh, const ushort* __restrict__ bc,
           const float* __restrict__ segb, const float* __restrict__ dtb_,
           const float* __restrict__ Dvec, const float* __restrict__ sbuf,
           const ushort* __restrict__ zb, ushort* __restrict__ gz,
           float* __restrict__ ssq)
{
    __shared__ __align__(16) char smem[66560];
    ushort* Ct  = (ushort*)smem;             // [128][64]  sw64  (C rows tau)
    ushort* XT  = (ushort*)(smem + 16384);   // [64][128]  sw128 (X^T: d, tau)
    ushort* Bt  = (ushort*)(smem + 32768);   // [128][64]  sw64  (dead after GEMM1)
    ushort* Wl  = (ushort*)(smem + 32768);   // [128][128] sw128 (overlaps Bt)
    float* segl = (float*)(smem + 65536);    // [128]
    float* dtl  = (float*)(smem + 66048);    // [128]

    const int tid = threadIdx.x;
    const int w = tid >> 6, lane = tid & 63;
    const int lm = lane & 15, quad = lane >> 4;
    const int c = blockIdx.x, h = blockIdx.y, b = blockIdx.z;
    const int bh = b * 16 + h;
    const size_t abase = (size_t)bh * LSEQ + c * QCH;
    int band[2]; band[0] = w; band[1] = 7 - w;

    if (tid < 128) {
        segl[tid] = segb[abase + tid];
        dtl[tid]  = dtb_[abase + tid];
    }
#pragma unroll
    for (int it = 0; it < 8; ++it) {
        int idx = it * 256 + tid;
        int tau = idx >> 4, e4 = (idx & 15) * 4;
        size_t grow = (size_t)b * LSEQ + (LSEQ - 1 - (c * QCH + tau));
        ushort4 bv = *(const ushort4*)(bc + grow * 128 + e4);
        ushort4 cv = *(const ushort4*)(bc + grow * 128 + 64 + e4);
        *(ushort4*)(Bt + sw64i(tau, e4)) = bv;
        *(ushort4*)(Ct + sw64i(tau, e4)) = cv;
        ushort4 xv = *(const ushort4*)(xh + grow * 1024 + h * 64 + e4);
        XT[sw128i(e4 + 0, tau)] = xv.x;
        XT[sw128i(e4 + 1, tau)] = xv.y;
        XT[sw128i(e4 + 2, tau)] = xv.z;
        XT[sw128i(e4 + 3, tau)] = xv.w;
    }
    // prefetch z-gate values into registers (latency hidden under GEMM1/W-gen)
    ushort zr[2][4][4];
#pragma unroll
    for (int i = 0; i < 2; ++i)
#pragma unroll
        for (int r = 0; r < 4; ++r) {
            const int tau = band[i] * 16 + quad * 4 + r;
            const size_t grow = (size_t)b * LSEQ + (LSEQ - 1 - (c * QCH + tau));
#pragma unroll
            for (int jn = 0; jn < 4; ++jn)
                zr[i][r][jn] = zb[grow * NPAD + h * 64 + jn * 16 + lm];
        }
    __syncthreads();

    // GEMM1: G = C . B^T over n; only jn-blocks <= band
    floatx4 G[2][8];
#pragma unroll
    for (int i = 0; i < 2; ++i)
#pragma unroll
        for (int j = 0; j < 8; ++j) G[i][j] = (floatx4){0.f, 0.f, 0.f, 0.f};
#pragma unroll
    for (int i = 0; i < 2; ++i) {
        const int bnd = band[i];
        short8 a0 = *(const short8*)(Ct + sw64i(bnd * 16 + lm, 0 * 32 + quad * 8));
        short8 a1 = *(const short8*)(Ct + sw64i(bnd * 16 + lm, 1 * 32 + quad * 8));
#pragma unroll
        for (int jn = 0; jn < 8; ++jn) {
            if (jn <= bnd) {
                short8 b0 = *(const short8*)(Bt + sw64i(jn * 16 + lm, 0 * 32 + quad * 8));
                short8 b1 = *(const short8*)(Bt + sw64i(jn * 16 + lm, 1 * 32 + quad * 8));
                G[i][jn] = __builtin_amdgcn_mfma_f32_16x16x32_bf16(a0, b0, G[i][jn], 0, 0, 0);
                G[i][jn] = __builtin_amdgcn_mfma_f32_16x16x32_bf16(a1, b1, G[i][jn], 0, 0, 0);
            }
        }
    }
    __syncthreads();   // everyone done reading Bt before Wl overwrites it

    const float Dh = Dvec[h];
#pragma unroll
    for (int i = 0; i < 2; ++i) {
        const int bnd = band[i];
        const int taub = bnd * 16;
#pragma unroll
        for (int jn = 0; jn < 8; ++jn) {
            const int sigma = jn * 16 + lm;
            if (jn < bnd) {              // all sigma < all tau
                const float dts = dtl[sigma];
                const float segs = segl[sigma];
#pragma unroll
                for (int r = 0; r < 4; ++r) {
                    const int tau = taub + quad * 4 + r;
                    float wv = dts * G[i][jn][r] * __expf(segl[tau] - segs);
                    Wl[sw128i(tau, sigma)] = f2bf(wv);
                }
            } else if (jn == bnd) {      // diagonal block
                const float dts = dtl[sigma];
                const float segs = segl[sigma];
#pragma unroll
                for (int r = 0; r < 4; ++r) {
                    const int tau = taub + quad * 4 + r;
                    float g = G[i][jn][r];
                    float wv;
                    if (sigma < tau)       wv = dts * g * __expf(segl[tau] - segs);
                    else if (sigma == tau) wv = dts * g + Dh;
                    else                   wv = 0.f;
                    Wl[sw128i(tau, sigma)] = f2bf(wv);
                }
            } else if (jn == bnd + 1 && (bnd & 1) == 0) {  // zero-fill read block
#pragma unroll
                for (int r = 0; r < 4; ++r)
                    Wl[sw128i(taub + quad * 4 + r, sigma)] = 0;
            }
        }
    }
    // no barrier needed: each wave reads back only its own W rows

    // GEMM2: Y = W.X (kc-blocks <= band/2 only); Y2 = C.h^T (separate acc)
    floatx4 Y[2][4], Y2[2][4];
#pragma unroll
    for (int i = 0; i < 2; ++i)
#pragma unroll
        for (int j = 0; j < 4; ++j) {
            Y[i][j]  = (floatx4){0.f, 0.f, 0.f, 0.f};
            Y2[i][j] = (floatx4){0.f, 0.f, 0.f, 0.f};
        }
#pragma unroll
    for (int kc = 0; kc < 4; ++kc) {
        short8 bfx[4];
#pragma unroll
        for (int jn = 0; jn < 4; ++jn)
            bfx[jn] = *(const short8*)(XT + sw128i(jn * 16 + lm, kc * 32 + quad * 8));
#pragma unroll
        for (int i = 0; i < 2; ++i) {
            if (kc <= (band[i] >> 1)) {
                short8 a = *(const short8*)(Wl + sw128i(band[i] * 16 + lm, kc * 32 + quad * 8));
#pragma unroll
                for (int jn = 0; jn < 4; ++jn)
                    Y[i][jn] = __builtin_amdgcn_mfma_f32_16x16x32_bf16(a, bfx[jn], Y[i][jn], 0, 0, 0);
            }
        }
    }
    // H-part: bf16 h from scan_combine, partitioned layout:
    // element (p,n) at ushort offset 2048*(p>>4) + (p&15)*64 + n
    const ushort* hb = (const ushort*)(sbuf + ((size_t)bh * NCH + c) * 4096);
#pragma unroll
    for (int kc = 0; kc < 2; ++kc) {
        short8 a2[2];
#pragma unroll
        for (int i = 0; i < 2; ++i)
            a2[i] = *(const short8*)(Ct + sw64i(band[i] * 16 + lm, kc * 32 + quad * 8));
#pragma unroll
        for (int jn = 0; jn < 4; ++jn) {
            short8 bfh = *(const short8*)(hb + jn * 2048 + lm * 64 + kc * 32 + quad * 8);
#pragma unroll
            for (int i = 0; i < 2; ++i)
                Y2[i][jn] = __builtin_amdgcn_mfma_f32_16x16x32_bf16(a2[i], bfh, Y2[i][jn], 0, 0, 0);
        }
    }

    // epilogue: Y + exp(seg)*Y2, z-gate, store bf16, per-row sum of squares
#pragma unroll
    for (int i = 0; i < 2; ++i) {
#pragma unroll
        for (int r = 0; r < 4; ++r) {
            const int tau = band[i] * 16 + quad * 4 + r;
            const float es = __expf(segl[tau]);
            const size_t grow = (size_t)b * LSEQ + (LSEQ - 1 - (c * QCH + tau));
            float part = 0.f;
#pragma unroll
            for (int jn = 0; jn < 4; ++jn) {
                const int col = h * 64 + jn * 16 + lm;
                float yv = Y[i][jn][r] + es * Y2[i][jn][r];
                float zv = bf2f(zr[i][r][jn]);
                float gv = yv * silu_f(zv);
                gz[grow * 1024 + col] = f2bf(gv);
                part += gv * gv;
            }
            part += __shfl_xor(part, 1);
            part += __shfl_xor(part, 2);
            part += __shfl_xor(part, 4);
            part += __shfl_xor(part, 8);
            if (lm == 0) atomicAdd(ssq + grow, part);
        }
    }
}

// ---------------------------------------------------------------------------
extern "C" void kernel_launch(void* const* d_in, const int* in_sizes, int n_in,
                              void* d_out, int out_size, void* d_ws, size_t ws_size,
                              hipStream_t stream)
{
    const float* x         = (const float*)d_in[0];
    const float* in_proj_w = (const float*)d_in[1];   // (2192, 512)
    const float* conv_w    = (const float*)d_in[2];   // (1152, 4)
    const float* conv_b    = (const float*)d_in[3];
    const float* dt_bias   = (const float*)d_in[4];   // (16,)
    const float* A_log     = (const float*)d_in[5];
    const float* Dv        = (const float*)d_in[6];
    const float* rms_w     = (const float*)d_in[7];
    const float* out_proj_w= (const float*)d_in[8];   // (512, 1024)
    const float* ln_g      = (const float*)d_in[9];
    const float* ln_b      = (const float*)d_in[10];
    const float* w1        = (const float*)d_in[11];  // (1024, 1024)
    const float* b1        = (const float*)d_in[12];
    const float* w2        = (const float*)d_in[13];  // (512, 1024)
    const float* b2        = (const float*)d_in[14];
    float* out = (float*)d_out;
    char* base = (char*)d_ws;

    // workspace layout (byte offsets), liveness-safe reuse:
    ushort* g1out = (ushort*)(base);                   // [T,2304] bf16   75.5 MB
    ushort* xh_b  = (ushort*)(base + 75497472);        // [T,1024] bf16   33.5 MB
    ushort* bc_b  = (ushort*)(base + 109051904);       // [T,128]  bf16    4.2 MB
    ushort* gz    = (ushort*)(base + 113246208);       // [T,1024] bf16   33.5 MB
    ushort* xbf   = (ushort*)(base + 113246208);       // [T,512] bf16 (dead before gz)
    float*  dtr   = (float*) (base + 146800640);       // [64][4096]       1 MB
    float*  segb  = (float*) (base + 148897792);       // [64][4096]       1 MB
    float*  alphab= (float*) (base + 149946368);       // [64][4096]       1 MB
    ushort* wip   = (ushort*)(base + 150994944);       // [2304,512] bf16
    ushort* w1g   = (ushort*)(base + 153354240);       // [1024,512] bf16 (ln_g folded)
    ushort* wopb  = (ushort*)(base + 154402816);       // [512,1024] bf16
    ushort* w2b   = (ushort*)(base + 155451392);       // [512,1024] bf16
    float*  Pbuf  = (float*) (base + 156499968);       // [2048]
    float*  ssqp  = (float*) (base + 156508160);       // [16384] rms ssq accum
    // LN stats live inside dtr's 1MB region (dtr dead after ssd_y):
    float*  invv = dtr;                                // [16384]
    float*  miv  = dtr + 16384;                        // [16384]
    // Sg/SB reuse wip (dead after in_proj; prep_rowsums runs after it).
    float*  Sg   = (float*)wip;
    float*  SB   = (float*)wip + 1024;
    // post-scan reuse:
    ushort* y2bf = (ushort*)(base + 33554432);         // [T,512] bf16 (g1out dead)
    ushort* h1  = gz;                                  // [T,1024] bf16 (gz dead after out_proj)
    // chunk states: 64 tiles/seq-head x 4096 f32 == out_size; d_out dead until MLP2
    float* sbuf = out;

    // ---- casts / weight prep ----
    cast_x_k<<<(TTOK * 512 / 4 + 255) / 256, 256, 0, stream>>>(
        (const float4*)x, (ushort4*)xbf, TTOK * 512 / 4);
    prep_weights<<<((NPAD * 512 + 1024 * 512 + 2 * 512 * 1024) / 4 + 255) / 256, 256, 0, stream>>>(
        in_proj_w, w1, out_proj_w, w2, rms_w, ln_g, wip, w1g, wopb, w2b);

    // ---- in_proj ----  (1-D grid, XCD swizzle inside; BK=32 -> 2 blocks/CU)
    gemm256<0, ushort, 256, 32><<<dim3((NPAD / 256) * (TTOK / 256)), 512, 0, stream>>>(
        xbf, wip, nullptr, nullptr, nullptr, nullptr, g1out, TTOK, NPAD, 512);

    // Sg/SB for the LN->MLP1 fold (wip region is dead from here on)
    prep_rowsums<<<256, 256, 0, stream>>>(w1, ln_g, ln_b, b1, Sg, SB);

    seg_scan<<<dim3(NCH, 16, 4), 128, 0, stream>>>(g1out, dt_bias, A_log, dtr, segb, alphab, Pbuf);
    conv_silu<<<((TTOK / CSTRIP) * 144 + 255) / 256, 256, 0, stream>>>(
        g1out, conv_w, conv_b, xh_b, bc_b);

    // ---- SSD chunked scan ----
    ssd_states  <<<dim3(NCH, 16, 4), 256, 0, stream>>>(xh_b, bc_b, alphab, sbuf);
    scan_combine<<<dim3(4, 16, 4),   256, 0, stream>>>(sbuf, Pbuf, ssqp);
    ssd_y       <<<dim3(NCH, 16, 4), 256, 0, stream>>>(xh_b, bc_b, segb, dtr, Dv,
                                                       sbuf, g1out, gz, ssqp);

    // ---- projections + MLP (rms fused into out_proj; LN folded into MLP1) ----
    gemm256<2, ushort, 128, 64><<<dim3((512 / 128) * (TTOK / 256)), 512, 0, stream>>>(
        gz, wopb, nullptr, ssqp, nullptr, nullptr, y2bf, TTOK, 512, 1024);
    ln_stats<<<TTOK / 16, 256, 0, stream>>>(y2bf, miv, invv);
    gemm256<5, ushort, 256, 64><<<dim3((1024 / 256) * (TTOK / 256)), 512, 0, stream>>>(
        y2bf, w1g, SB, miv, invv, Sg, h1, TTOK, 1024, 512);
    gemm256<0, float, 128, 64><<<dim3((512 / 128) * (TTOK / 256)), 512, 0, stream>>>(
        h1, w2b, b2, nullptr, nullptr, nullptr, out, TTOK, 512, 1024);
}

// Round 9
// 394.034 us; speedup vs baseline: 1.0267x; 1.0267x over previous
//
#include <hip/hip_runtime.h>
#include <cstddef>
#include <cstdint>
#include <math.h>

// Problem constants
#define LSEQ   4096
#define BATCH  4
#define TTOK   (LSEQ * BATCH)      // 16384 rows
#define QCH    128                 // scan chunk length
#define NCH    (LSEQ / QCH)        // 32 chunks per sequence
#define NPAD   2304                // in_proj N padded to 18*128
// D_MODEL=512, D_INNER=1024, CONV_DIM=1152, NHEADS=16, HEADDIM=64, D_STATE=64
// g1out layout (ld 2304): [0,1024) z | [1024,2176) xBC | [2176,2192) dt_raw | pad
// Scan runs in reversed-time index r = 4095 - l (forward scan in r).
// rms scale KEPT (rounds 4-6 lesson: LN-invariance fails for tiny-norm rows
// because the rms eps floors them). LN folded into MLP1 (exact algebra).
// in_proj BK=64 (round-8 lesson: BK=32 regressed — no co-residency appeared,
// and the 4-chunk swizzle reintroduced bank conflicts).

typedef __attribute__((ext_vector_type(8))) short short8;
typedef __attribute__((ext_vector_type(8))) unsigned short ushortx8;
typedef __attribute__((ext_vector_type(4))) float floatx4;

// ---- bf16 helpers (manual, RNE) ----
__device__ __forceinline__ float bf2f(ushort u) {
    union { unsigned int i; float f; } v; v.i = ((unsigned int)u) << 16; return v.f;
}
__device__ __forceinline__ ushort f2bf(float f) {
    union { float f; unsigned int i; } v; v.f = f;
    unsigned int r = v.i + 0x7fffu + ((v.i >> 16) & 1u);
    return (ushort)(r >> 16);
}
__device__ __forceinline__ float silu_f(float a) {
    return a / (1.f + __expf(-a));
}

__device__ __forceinline__ void storev(float* p, float v)  { *p = v; }
__device__ __forceinline__ void storev(ushort* p, float v) { *p = f2bf(v); }

// 16B-chunk XOR swizzles for LDS tiles (conflict-free b128 frag reads)
__device__ __forceinline__ int sw64i(int row, int col) {
    return row * 64 + ((((col >> 3) ^ row) & 7) << 3) + (col & 7);
}
__device__ __forceinline__ int sw128i(int row, int col) {
    return row * 128 + ((((col >> 3) ^ row) & 15) << 3) + (col & 7);
}

// async 16B global -> LDS (wave-uniform LDS base + lane*16)
__device__ __forceinline__ void gload_lds16(const ushort* g, short* l) {
    __builtin_amdgcn_global_load_lds(
        (const __attribute__((address_space(1))) void*)g,
        (__attribute__((address_space(3))) void*)l, 16, 0, 0);
}

// raw waits / barriers (NO __syncthreads in the GEMM: it would drain vmcnt)
__device__ __forceinline__ void vmwait4() { asm volatile("s_waitcnt vmcnt(4)" ::: "memory"); }
__device__ __forceinline__ void vmwait3() { asm volatile("s_waitcnt vmcnt(3)" ::: "memory"); }
__device__ __forceinline__ void vmwait0() { asm volatile("s_waitcnt vmcnt(0)" ::: "memory"); }
__device__ __forceinline__ void wgbar() {
    __builtin_amdgcn_sched_barrier(0);
    __builtin_amdgcn_s_barrier();
    __builtin_amdgcn_sched_barrier(0);
}

// ---------------------------------------------------------------------------
// 256x{256,128} 8-phase bf16 MFMA GEMM: C[M,N] = epi(A[M,K] @ W[N,K]^T + bias)
// EPI: 0 none | 1 silu
//      2 rms row-scale: v *= rsqrt(aux[row]/1024 + eps)
//      5 fused-LayerNorm affine + silu:
//        v = silu(acc*inv - mi*aux3[col] + bias[col]); mi=aux[row], inv=aux2[row]
// ---------------------------------------------------------------------------
template<int EPI, typename OutT, int BN>
__global__ __launch_bounds__(512, 2)
void gemm256(const ushort* __restrict__ A, const ushort* __restrict__ W,
             const float* __restrict__ bias, const float* __restrict__ aux,
             const float* __restrict__ aux2, const float* __restrict__ aux3,
             OutT* __restrict__ C, int M, int N, int K)
{
    constexpr int BHALF = (BN == 256) ? 8192 : 4096;  // shorts per B half-region
    constexpr int BLD   = (BN == 256) ? 2 : 1;        // gloads/thread per B half
    constexpr int NFH   = (BN == 256) ? 2 : 1;        // B frags per N-half per wave
    __shared__ __align__(16) short As[4 * 8192];      // 2 buf x 2 half x [128][64]
    __shared__ __align__(16) short Bs[4 * BHALF];     // 2 buf x 2 half x [BN/2][64]

    const int tid = threadIdx.x;
    const int w = tid >> 6, lane = tid & 63;
    const int lm = lane & 15, quad = lane >> 4;
    const int wm = w & 1, wn = w >> 1;

    // XCD-chunked bijective swizzle (nwg % 8 == 0 for all our grids)
    const int nwg = gridDim.x;
    const int chunk = nwg >> 3;
    const int bid = blockIdx.x;
    const int vid = (bid & 7) * chunk + (bid >> 3);
    const int NX = N / BN;
    const int bx = vid % NX, by = vid / NX;
    const int m0 = by * 256, n0 = bx * BN;
    const int NT = K >> 6;                            // K-tiles (>= 8 here)

    const int srow = tid >> 3;
    const int scol = ((tid & 7) ^ (srow & 7)) * 8;
    const ushort* ga = A + (size_t)(m0 + srow) * K + scol;
    const ushort* gb = W + (size_t)(n0 + srow) * K + scol;
    short* lA = As + w * 512;
    short* lB = Bs + w * 512;

    auto STAGE_A = [&](int bf, int h, int kt) {
        const ushort* g = ga + (size_t)(h * 128) * K + kt * 64;
        short* l = lA + bf * 16384 + h * 8192;
        gload_lds16(g, l);
        gload_lds16(g + (size_t)64 * K, l + 4096);
    };
    auto STAGE_B = [&](int bf, int h, int kt) {
        const ushort* g = gb + (size_t)(h * (BN / 2)) * K + kt * 64;
        short* l = lB + bf * 2 * BHALF + h * BHALF;
        gload_lds16(g, l);
        if constexpr (BLD == 2) gload_lds16(g + (size_t)64 * K, l + 4096);
    };

    int aRow[4], bRow[NFH], kch[2];
#pragma unroll
    for (int i = 0; i < 4; ++i) aRow[i] = ((i * 2 + wm) * 16 + lm) * 64;
#pragma unroll
    for (int j = 0; j < NFH; ++j) bRow[j] = ((j * 4 + wn) * 16 + lm) * 64;
#pragma unroll
    for (int ks = 0; ks < 2; ++ks) kch[ks] = (((ks * 4 + quad) ^ (lm & 7)) * 8);

    floatx4 acc[8][2 * NFH];
#pragma unroll
    for (int i = 0; i < 8; ++i)
#pragma unroll
        for (int j = 0; j < 2 * NFH; ++j) acc[i][j] = (floatx4){0.f, 0.f, 0.f, 0.f};
    short8 af[4][2], bfr[NFH][2];

#define G_LOADA(bfv, MH)                                                      \
    {                                                                         \
        const short* _ba = As + (bfv) * 16384 + (MH) * 8192;                  \
        _Pragma("unroll")                                                     \
        for (int _i = 0; _i < 4; ++_i)                                        \
            _Pragma("unroll")                                                 \
            for (int _k = 0; _k < 2; ++_k)                                    \
                af[_i][_k] = *(const short8*)(_ba + aRow[_i] + kch[_k]);      \
    }
#define G_LOADB(bfv, NH)                                                      \
    {                                                                         \
        const short* _bb = Bs + (bfv) * 2 * BHALF + (NH) * BHALF;             \
        _Pragma("unroll")                                                     \
        for (int _j = 0; _j < NFH; ++_j)                                      \
            _Pragma("unroll")                                                 \
            for (int _k = 0; _k < 2; ++_k)                                    \
                bfr[_j][_k] = *(const short8*)(_bb + bRow[_j] + kch[_k]);     \
    }
#define G_MMA(MH, NH)                                                         \
    {                                                                         \
        __builtin_amdgcn_s_setprio(1);                                        \
        _Pragma("unroll")                                                     \
        for (int _i = 0; _i < 4; ++_i)                                        \
            _Pragma("unroll")                                                 \
            for (int _j = 0; _j < NFH; ++_j)                                  \
                _Pragma("unroll")                                             \
                for (int _k = 0; _k < 2; ++_k)                                \
                    acc[(MH) * 4 + _i][(NH) * NFH + _j] =                     \
                        __builtin_amdgcn_mfma_f32_16x16x32_bf16(              \
                            af[_i][_k], bfr[_j][_k],                          \
                            acc[(MH) * 4 + _i][(NH) * NFH + _j], 0, 0, 0);    \
        __builtin_amdgcn_s_setprio(0);                                        \
    }

    STAGE_A(0, 0, 0); STAGE_B(0, 0, 0); STAGE_B(0, 1, 0); STAGE_A(0, 1, 0);
    STAGE_A(1, 0, 1); STAGE_B(1, 1, 1);
    if constexpr (BLD == 2) vmwait4(); else vmwait3();
    wgbar();

    for (int t = 0; t < NT; ++t) {
        const int bf = t & 1;
        G_LOADA(bf, 0); G_LOADB(bf, 0);
        if (t + 1 < NT) STAGE_B(bf ^ 1, 0, t + 1);
        wgbar();
        G_MMA(0, 0);
        wgbar();
        G_LOADB(bf, 1);
        if (t + 1 < NT) STAGE_A(bf ^ 1, 1, t + 1);
        wgbar();
        G_MMA(0, 1);
        wgbar();
        G_LOADA(bf, 1);
        if (t + 2 < NT) STAGE_A(bf, 0, t + 2);
        wgbar();
        G_MMA(1, 1);
        wgbar();
        G_LOADB(bf, 0);
        if (t + 2 < NT) STAGE_B(bf, 1, t + 2);
        wgbar();
        G_MMA(1, 0);
        __builtin_amdgcn_sched_barrier(0);
        if (t + 2 < NT) { if constexpr (BLD == 2) vmwait4(); else vmwait3(); }
        else if (t + 1 < NT) vmwait0();
        wgbar();
    }
#undef G_LOADA
#undef G_LOADB
#undef G_MMA

    // epilogue
#pragma unroll
    for (int ii = 0; ii < 8; ++ii) {
        const int rb = m0 + (ii * 2 + wm) * 16 + quad * 4;
#pragma unroll
        for (int rr = 0; rr < 4; ++rr) {
            const int row = rb + rr;
            float inv = 1.f, mi = 0.f, scale = 1.f;
            if (EPI == 2) scale = rsqrtf(aux[row] * (1.f / 1024.f) + 1e-5f);
            if (EPI == 5) { mi = aux[row]; inv = aux2[row]; }
#pragma unroll
            for (int jj = 0; jj < 2 * NFH; ++jj) {
                const int col = n0 + (jj * 4 + wn) * 16 + lm;
                float v = acc[ii][jj][rr];
                if (EPI == 5) {
                    v = silu_f(v * inv - mi * aux3[col] + bias[col]);
                } else {
                    if (bias) v += bias[col];
                    if (EPI == 1) v = silu_f(v);
                    if (EPI == 2) v *= scale;
                }
                storev(&C[(size_t)row * N + col], v);
            }
        }
    }
}

// ---------------------------------------------------------------------------
// casts
// ---------------------------------------------------------------------------
__global__ __launch_bounds__(256)
void cast_x_k(const float4* __restrict__ in, ushort4* __restrict__ out, int n4)
{
    int i = blockIdx.x * 256 + threadIdx.x;
    if (i >= n4) return;
    float4 v = in[i];
    ushort4 o;
    o.x = f2bf(v.x); o.y = f2bf(v.y); o.z = f2bf(v.z); o.w = f2bf(v.w);
    out[i] = o;
}

// weight preps: in_proj pad, w1 fold (+ln_g fold), out_proj*rms_w, w2
__global__ __launch_bounds__(256)
void prep_weights(const float* __restrict__ ipw, const float* __restrict__ w1,
                  const float* __restrict__ wop, const float* __restrict__ w2,
                  const float* __restrict__ rw, const float* __restrict__ lng,
                  ushort* __restrict__ wip, ushort* __restrict__ w1g,
                  ushort* __restrict__ wopb, ushort* __restrict__ w2b)
{
    int i4 = (blockIdx.x * 256 + threadIdx.x) * 4;
    if (i4 < NPAD * 512) {
        int row = i4 >> 9;
        ushort4 v;
        if (row < 2192) {
            float4 s = *(const float4*)(ipw + (size_t)i4);
            v.x = f2bf(s.x); v.y = f2bf(s.y); v.z = f2bf(s.z); v.w = f2bf(s.w);
        } else { v.x = v.y = v.z = v.w = 0; }
        *(ushort4*)(wip + i4) = v;
        return;
    }
    i4 -= NPAD * 512;
    if (i4 < 1024 * 512) {
        int j = i4 >> 9, d = i4 & 511;
        float4 a = *(const float4*)(w1 + (size_t)j * 1024 + d);
        float4 b = *(const float4*)(w1 + (size_t)j * 1024 + 512 + d);
        float4 g = *(const float4*)(lng + d);
        ushort4 v;
        v.x = f2bf((a.x + b.x) * g.x); v.y = f2bf((a.y + b.y) * g.y);
        v.z = f2bf((a.z + b.z) * g.z); v.w = f2bf((a.w + b.w) * g.w);
        *(ushort4*)(w1g + i4) = v;
        return;
    }
    i4 -= 1024 * 512;
    if (i4 < 512 * 1024) {
        float4 s = *(const float4*)(wop + (size_t)i4);
        float4 g = *(const float4*)(rw + (i4 & 1023));
        ushort4 v;
        v.x = f2bf(s.x * g.x); v.y = f2bf(s.y * g.y);
        v.z = f2bf(s.z * g.z); v.w = f2bf(s.w * g.w);
        *(ushort4*)(wopb + i4) = v;
        return;
    }
    i4 -= 512 * 1024;
    if (i4 < 512 * 1024) {
        float4 s = *(const float4*)(w2 + (size_t)i4);
        ushort4 v;
        v.x = f2bf(s.x); v.y = f2bf(s.y); v.z = f2bf(s.z); v.w = f2bf(s.w);
        *(ushort4*)(w2b + i4) = v;
    }
}

// row-sums for the LN->MLP1 fold: Sg[n] = sum_k w1f[n,k]*ln_g[k],
// SB[n] = sum_k w1f[n,k]*ln_b[k] + b1[n], with w1f = w1[:, :512]+w1[:, 512:].
__global__ __launch_bounds__(256)
void prep_rowsums(const float* __restrict__ w1, const float* __restrict__ g,
                  const float* __restrict__ bb, const float* __restrict__ b1,
                  float* __restrict__ Sg, float* __restrict__ SB)
{
    const int n = blockIdx.x * 4 + (threadIdx.x >> 6);
    const int lane = threadIdx.x & 63;
    float sg = 0.f, sb = 0.f;
#pragma unroll
    for (int it = 0; it < 8; ++it) {
        int k = it * 64 + lane;
        float wv = w1[(size_t)n * 1024 + k] + w1[(size_t)n * 1024 + 512 + k];
        sg += wv * g[k];
        sb += wv * bb[k];
    }
#pragma unroll
    for (int off = 32; off > 0; off >>= 1) {
        sg += __shfl_xor(sg, off);
        sb += __shfl_xor(sb, off);
    }
    if (lane == 0) { Sg[n] = sg; SB[n] = sb + b1[n]; }
}

// ---------------------------------------------------------------------------
// LN row stats from bf16 y2 (already rms-scaled): one wave per row.
// Writes mi = mean*inv and inv = rsqrt(var+eps).
// ---------------------------------------------------------------------------
__global__ __launch_bounds__(256)
void ln_stats(const ushort* __restrict__ y2, float* __restrict__ miv,
              float* __restrict__ invv)
{
    const int w = threadIdx.x >> 6, lane = threadIdx.x & 63;
#pragma unroll
    for (int it = 0; it < 4; ++it) {
        const int row = blockIdx.x * 16 + it * 4 + w;
        ushortx8 v = *(const ushortx8*)(y2 + (size_t)row * 512 + lane * 8);
        float s = 0.f, ss = 0.f;
#pragma unroll
        for (int e = 0; e < 8; ++e) { float f = bf2f(v[e]); s += f; ss += f * f; }
#pragma unroll
        for (int off = 32; off > 0; off >>= 1) {
            s += __shfl_xor(s, off);
            ss += __shfl_xor(ss, off);
        }
        if (lane == 0) {
            float mean = s * (1.f / 512.f);
            float var  = ss * (1.f / 512.f) - mean * mean;
            float inv  = rsqrtf(var + 1e-5f);
            miv[row]  = mean * inv;
            invv[row] = inv;
        }
    }
}

// ---------------------------------------------------------------------------
// seg_scan (dt fused)
// ---------------------------------------------------------------------------
__global__ __launch_bounds__(128)
void seg_scan(const ushort* __restrict__ raw, const float* __restrict__ dt_bias,
              const float* __restrict__ A_log, float* __restrict__ dtr,
              float* __restrict__ segb, float* __restrict__ alphab,
              float* __restrict__ Pb)
{
    __shared__ float s[128];
    const int tid = threadIdx.x;
    const int c = blockIdx.x, h = blockIdx.y, b = blockIdx.z;
    const int bh = b * 16 + h;
    const int r = c * QCH + tid;
    const size_t grow = (size_t)b * LSEQ + (LSEQ - 1 - r);
    const size_t idx = (size_t)bh * LSEQ + r;

    float v = bf2f(raw[grow * NPAD + 2176 + h]) + dt_bias[h];
    float dt = (v > 20.f) ? v : log1pf(expf(v));
    float Ah = -expf(A_log[h]);
    s[tid] = dt * Ah;
    __syncthreads();
#pragma unroll
    for (int off = 1; off < 128; off <<= 1) {
        float t = (tid >= off) ? s[tid - off] : 0.f;
        __syncthreads();
        s[tid] += t;
        __syncthreads();
    }
    float seg = s[tid];
    float last = s[127];
    dtr[idx] = dt;
    segb[idx] = seg;
    alphab[idx] = __expf(last - seg) * dt;
    if (tid == 127) Pb[bh * NCH + c] = __expf(last);
}

// ---------------------------------------------------------------------------
// Anti-causal depthwise conv + silu, rolling-window.
// ---------------------------------------------------------------------------
#define CSTRIP 8
__global__ __launch_bounds__(256)
void conv_silu(const ushort* __restrict__ raw, const float* __restrict__ cw,
               const float* __restrict__ cb, ushort* __restrict__ xh,
               ushort* __restrict__ bc)
{
    const int idx = blockIdx.x * 256 + threadIdx.x;   // over (TTOK/CSTRIP)*144
    if (idx >= (TTOK / CSTRIP) * 144) return;
    const int strip = idx / 144;
    const int g = idx - strip * 144;
    const int c0 = g * 8;
    const int row0 = strip * CSTRIP;                  // global first row
    const int l0 = row0 & (LSEQ - 1);

    float wt[4][8];
    float bias[8];
#pragma unroll
    for (int e = 0; e < 8; ++e) {
        float4 a = *(const float4*)(cw + (c0 + e) * 4);
        wt[0][e] = a.w; wt[1][e] = a.z; wt[2][e] = a.y; wt[3][e] = a.x;
        bias[e] = cb[c0 + e];
    }

    float win[4][8];
    auto loadrow = [&](int l, float* dst) {
        if (l < LSEQ) {
            ushortx8 v = *(const ushortx8*)(raw + (size_t)(row0 - l0 + l) * NPAD + 1024 + c0);
#pragma unroll
            for (int e = 0; e < 8; ++e) dst[e] = bf2f(v[e]);
        } else {
#pragma unroll
            for (int e = 0; e < 8; ++e) dst[e] = 0.f;
        }
    };

    {
        const int ltop = l0 + CSTRIP - 1;
        loadrow(ltop + 1, win[(ltop + 1) & 3]);
        loadrow(ltop + 2, win[(ltop + 2) & 3]);
        loadrow(ltop + 3, win[(ltop + 3) & 3]);
    }
#pragma unroll
    for (int s = CSTRIP - 1; s >= 0; --s) {
        const int l = l0 + s;
        loadrow(l, win[l & 3]);
        ushortx8 o;
#pragma unroll
        for (int e = 0; e < 8; ++e) {
            float acc = bias[e];
#pragma unroll
            for (int j = 0; j < 4; ++j)
                acc = fmaf(wt[j][e], win[(l + j) & 3][e], acc);
            o[e] = f2bf(silu_f(acc));
        }
        const size_t row = (size_t)row0 + s;
        if (c0 < 1024) *(ushortx8*)(xh + row * 1024 + c0) = o;
        else           *(ushortx8*)(bc + row * 128 + (c0 - 1024)) = o;
    }
}

// ---------------------------------------------------------------------------
// SSD pass A: per tile (c,h,b), chunk end-state
// ---------------------------------------------------------------------------
__global__ __launch_bounds__(256)
void ssd_states(const ushort* __restrict__ xh, const ushort* __restrict__ bc,
                const float* __restrict__ alphab, float* __restrict__ sbuf)
{
    __shared__ __align__(16) ushort XT[64 * 128];
    __shared__ __align__(16) ushort BpT[64 * 128];
    const int tid = threadIdx.x;
    const int w = tid >> 6, lane = tid & 63;
    const int lm = lane & 15, quad = lane >> 4;
    const int c = blockIdx.x, h = blockIdx.y, b = blockIdx.z;
    const int bh = b * 16 + h;
    const size_t abase = (size_t)bh * LSEQ + c * QCH;

#pragma unroll
    for (int it = 0; it < 8; ++it) {
        int idx = it * 256 + tid;
        int tau = idx >> 4, e4 = (idx & 15) * 4;
        size_t grow = (size_t)b * LSEQ + (LSEQ - 1 - (c * QCH + tau));
        ushort4 xv = *(const ushort4*)(xh + grow * 1024 + h * 64 + e4);
        XT[sw128i(e4 + 0, tau)] = xv.x;
        XT[sw128i(e4 + 1, tau)] = xv.y;
        XT[sw128i(e4 + 2, tau)] = xv.z;
        XT[sw128i(e4 + 3, tau)] = xv.w;
        float al = alphab[abase + tau];
        ushort4 bv = *(const ushort4*)(bc + grow * 128 + e4);
        BpT[sw128i(e4 + 0, tau)] = f2bf(bf2f(bv.x) * al);
        BpT[sw128i(e4 + 1, tau)] = f2bf(bf2f(bv.y) * al);
        BpT[sw128i(e4 + 2, tau)] = f2bf(bf2f(bv.z) * al);
        BpT[sw128i(e4 + 3, tau)] = f2bf(bf2f(bv.w) * al);
    }
    __syncthreads();

    floatx4 L[4];
#pragma unroll
    for (int j = 0; j < 4; ++j) L[j] = (floatx4){0.f, 0.f, 0.f, 0.f};
#pragma unroll
    for (int kc = 0; kc < 4; ++kc) {
        short8 a = *(const short8*)(XT + sw128i(w * 16 + lm, kc * 32 + quad * 8));
#pragma unroll
        for (int jn = 0; jn < 4; ++jn) {
            short8 bf = *(const short8*)(BpT + sw128i(jn * 16 + lm, kc * 32 + quad * 8));
            L[jn] = __builtin_amdgcn_mfma_f32_16x16x32_bf16(a, bf, L[jn], 0, 0, 0);
        }
    }
    float* Sp = sbuf + ((size_t)bh * NCH + c) * 4096;
#pragma unroll
    for (int jn = 0; jn < 4; ++jn)
#pragma unroll
        for (int r = 0; r < 4; ++r) {
            int p = w * 16 + quad * 4 + r;
            Sp[p * 64 + jn * 16 + lm] = L[jn][r];
        }
}

// ---------------------------------------------------------------------------
// Combine: sequential over chunks in scan (r) order with DEPTH-4 prefetch
// (the serial chain is one strided HBM/L2 round-trip per iteration; 4 loads
// in flight cut the per-iteration latency requirement ~4x). Fully unrolled
// so the nx[4] rotation uses static indices (no scratch, rule #20).
// Writes the chunk-start state h as PACKED BF16 (block-partitioned layout:
// block q writes only ushort [2048q,+1024) = f32 region it reads; the
// per-iteration barrier orders slot-c reads (4 iters earlier) before writes).
// q==0 blocks also zero the per-row ssq accumulator for the rms fusion.
// ---------------------------------------------------------------------------
__global__ __launch_bounds__(256)
void scan_combine(float* __restrict__ sbuf, const float* __restrict__ Pb,
                  float* __restrict__ ssq)
{
    const int tid = threadIdx.x;
    const int q = blockIdx.x, h = blockIdx.y, b = blockIdx.z;
    const int bh = b * 16 + h;
    if (q == 0) ssq[(size_t)bh * 256 + tid] = 0.f;
    const int off = q * 1024 + tid * 4;
    float c0 = 0.f, c1 = 0.f, c2 = 0.f, c3 = 0.f;

    float* slotbase = sbuf + (size_t)bh * NCH * 4096;
    float* sp0 = slotbase + off;
    const float* Pp = Pb + bh * NCH;

    float4 nx[4];
    float Pn[4];
#pragma unroll
    for (int d = 0; d < 4; ++d) {
        nx[d] = *(const float4*)(sp0 + (size_t)d * 4096);
        Pn[d] = Pp[d];
    }
#pragma unroll
    for (int c = 0; c < NCH; ++c) {
        float4 lv = nx[c & 3];
        float P  = Pn[c & 3];
        if (c + 4 < NCH) {
            nx[c & 3] = *(const float4*)(sp0 + (size_t)(c + 4) * 4096);
            Pn[c & 3] = Pp[c + 4];
        }
        __syncthreads();   // slot-c reads (iter c-4) done before slot-c writes
        ushort* hdst = (ushort*)(slotbase + (size_t)c * 4096) + q * 2048 + tid * 4;
        ushort4 hv;
        hv.x = f2bf(c0); hv.y = f2bf(c1); hv.z = f2bf(c2); hv.w = f2bf(c3);
        *(ushort4*)hdst = hv;
        c0 = fmaf(c0, P, lv.x);
        c1 = fmaf(c1, P, lv.y);
        c2 = fmaf(c2, P, lv.z);
        c3 = fmaf(c3, P, lv.w);
    }
}

// ---------------------------------------------------------------------------
// SSD pass C: Y = [M o (C B^T)] X + diag(exp(seg)) C h_start^T, D on diag,
// z-gate fused, writes gated bf16 + atomic per-row ssq (rms fusion).
// Triangular skip with balanced bands.
// ---------------------------------------------------------------------------
__global__ __launch_bounds__(256)
void ssd_y(const ushort* __restrict__ xh, const ushort* __restrict__ bc,
           const float* __restrict__ segb, const float* __restrict__ dtb_,
           const float* __restrict__ Dvec, const float* __restrict__ sbuf,
           const ushort* __restrict__ zb, ushort* __restrict__ gz,
           float* __restrict__ ssq)
{
    __shared__ __align__(16) char smem[66560];
    ushort* Ct  = (ushort*)smem;             // [128][64]  sw64  (C rows tau)
    ushort* XT  = (ushort*)(smem + 16384);   // [64][128]  sw128 (X^T: d, tau)
    ushort* Bt  = (ushort*)(smem + 32768);   // [128][64]  sw64  (dead after GEMM1)
    ushort* Wl  = (ushort*)(smem + 32768);   // [128][128] sw128 (overlaps Bt)
    float* segl = (float*)(smem + 65536);    // [128]
    float* dtl  = (float*)(smem + 66048);    // [128]

    const int tid = threadIdx.x;
    const int w = tid >> 6, lane = tid & 63;
    const int lm = lane & 15, quad = lane >> 4;
    const int c = blockIdx.x, h = blockIdx.y, b = blockIdx.z;
    const int bh = b * 16 + h;
    const size_t abase = (size_t)bh * LSEQ + c * QCH;
    int band[2]; band[0] = w; band[1] = 7 - w;

    if (tid < 128) {
        segl[tid] = segb[abase + tid];
        dtl[tid]  = dtb_[abase + tid];
    }
#pragma unroll
    for (int it = 0; it < 8; ++it) {
        int idx = it * 256 + tid;
        int tau = idx >> 4, e4 = (idx & 15) * 4;
        size_t grow = (size_t)b * LSEQ + (LSEQ - 1 - (c * QCH + tau));
        ushort4 bv = *(const ushort4*)(bc + grow * 128 + e4);
        ushort4 cv = *(const ushort4*)(bc + grow * 128 + 64 + e4);
        *(ushort4*)(Bt + sw64i(tau, e4)) = bv;
        *(ushort4*)(Ct + sw64i(tau, e4)) = cv;
        ushort4 xv = *(const ushort4*)(xh + grow * 1024 + h * 64 + e4);
        XT[sw128i(e4 + 0, tau)] = xv.x;
        XT[sw128i(e4 + 1, tau)] = xv.y;
        XT[sw128i(e4 + 2, tau)] = xv.z;
        XT[sw128i(e4 + 3, tau)] = xv.w;
    }
    // prefetch z-gate values into registers (latency hidden under GEMM1/W-gen)
    ushort zr[2][4][4];
#pragma unroll
    for (int i = 0; i < 2; ++i)
#pragma unroll
        for (int r = 0; r < 4; ++r) {
            const int tau = band[i] * 16 + quad * 4 + r;
            const size_t grow = (size_t)b * LSEQ + (LSEQ - 1 - (c * QCH + tau));
#pragma unroll
            for (int jn = 0; jn < 4; ++jn)
                zr[i][r][jn] = zb[grow * NPAD + h * 64 + jn * 16 + lm];
        }
    __syncthreads();

    // GEMM1: G = C . B^T over n; only jn-blocks <= band
    floatx4 G[2][8];
#pragma unroll
    for (int i = 0; i < 2; ++i)
#pragma unroll
        for (int j = 0; j < 8; ++j) G[i][j] = (floatx4){0.f, 0.f, 0.f, 0.f};
#pragma unroll
    for (int i = 0; i < 2; ++i) {
        const int bnd = band[i];
        short8 a0 = *(const short8*)(Ct + sw64i(bnd * 16 + lm, 0 * 32 + quad * 8));
        short8 a1 = *(const short8*)(Ct + sw64i(bnd * 16 + lm, 1 * 32 + quad * 8));
#pragma unroll
        for (int jn = 0; jn < 8; ++jn) {
            if (jn <= bnd) {
                short8 b0 = *(const short8*)(Bt + sw64i(jn * 16 + lm, 0 * 32 + quad * 8));
                short8 b1 = *(const short8*)(Bt + sw64i(jn * 16 + lm, 1 * 32 + quad * 8));
                G[i][jn] = __builtin_amdgcn_mfma_f32_16x16x32_bf16(a0, b0, G[i][jn], 0, 0, 0);
                G[i][jn] = __builtin_amdgcn_mfma_f32_16x16x32_bf16(a1, b1, G[i][jn], 0, 0, 0);
            }
        }
    }
    __syncthreads();   // everyone done reading Bt before Wl overwrites it

    const float Dh = Dvec[h];
#pragma unroll
    for (int i = 0; i < 2; ++i) {
        const int bnd = band[i];
        const int taub = bnd * 16;
#pragma unroll
        for (int jn = 0; jn < 8; ++jn) {
            const int sigma = jn * 16 + lm;
            if (jn < bnd) {              // all sigma < all tau
                const float dts = dtl[sigma];
                const float segs = segl[sigma];
#pragma unroll
                for (int r = 0; r < 4; ++r) {
                    const int tau = taub + quad * 4 + r;
                    float wv = dts * G[i][jn][r] * __expf(segl[tau] - segs);
                    Wl[sw128i(tau, sigma)] = f2bf(wv);
                }
            } else if (jn == bnd) {      // diagonal block
                const float dts = dtl[sigma];
                const float segs = segl[sigma];
#pragma unroll
                for (int r = 0; r < 4; ++r) {
                    const int tau = taub + quad * 4 + r;
                    float g = G[i][jn][r];
                    float wv;
                    if (sigma < tau)       wv = dts * g * __expf(segl[tau] - segs);
                    else if (sigma == tau) wv = dts * g + Dh;
                    else                   wv = 0.f;
                    Wl[sw128i(tau, sigma)] = f2bf(wv);
                }
            } else if (jn == bnd + 1 && (bnd & 1) == 0) {  // zero-fill read block
#pragma unroll
                for (int r = 0; r < 4; ++r)
                    Wl[sw128i(taub + quad * 4 + r, sigma)] = 0;
            }
        }
    }
    // no barrier needed: each wave reads back only its own W rows

    // GEMM2: Y = W.X (kc-blocks <= band/2 only); Y2 = C.h^T (separate acc)
    floatx4 Y[2][4], Y2[2][4];
#pragma unroll
    for (int i = 0; i < 2; ++i)
#pragma unroll
        for (int j = 0; j < 4; ++j) {
            Y[i][j]  = (floatx4){0.f, 0.f, 0.f, 0.f};
            Y2[i][j] = (floatx4){0.f, 0.f, 0.f, 0.f};
        }
#pragma unroll
    for (int kc = 0; kc < 4; ++kc) {
        short8 bfx[4];
#pragma unroll
        for (int jn = 0; jn < 4; ++jn)
            bfx[jn] = *(const short8*)(XT + sw128i(jn * 16 + lm, kc * 32 + quad * 8));
#pragma unroll
        for (int i = 0; i < 2; ++i) {
            if (kc <= (band[i] >> 1)) {
                short8 a = *(const short8*)(Wl + sw128i(band[i] * 16 + lm, kc * 32 + quad * 8));
#pragma unroll
                for (int jn = 0; jn < 4; ++jn)
                    Y[i][jn] = __builtin_amdgcn_mfma_f32_16x16x32_bf16(a, bfx[jn], Y[i][jn], 0, 0, 0);
            }
        }
    }
    // H-part: bf16 h from scan_combine, partitioned layout:
    // element (p,n) at ushort offset 2048*(p>>4) + (p&15)*64 + n
    const ushort* hb = (const ushort*)(sbuf + ((size_t)bh * NCH + c) * 4096);
#pragma unroll
    for (int kc = 0; kc < 2; ++kc) {
        short8 a2[2];
#pragma unroll
        for (int i = 0; i < 2; ++i)
            a2[i] = *(const short8*)(Ct + sw64i(band[i] * 16 + lm, kc * 32 + quad * 8));
#pragma unroll
        for (int jn = 0; jn < 4; ++jn) {
            short8 bfh = *(const short8*)(hb + jn * 2048 + lm * 64 + kc * 32 + quad * 8);
#pragma unroll
            for (int i = 0; i < 2; ++i)
                Y2[i][jn] = __builtin_amdgcn_mfma_f32_16x16x32_bf16(a2[i], bfh, Y2[i][jn], 0, 0, 0);
        }
    }

    // epilogue: Y + exp(seg)*Y2, z-gate, store bf16, per-row sum of squares
#pragma unroll
    for (int i = 0; i < 2; ++i) {
#pragma unroll
        for (int r = 0; r < 4; ++r) {
            const int tau = band[i] * 16 + quad * 4 + r;
            const float es = __expf(segl[tau]);
            const size_t grow = (size_t)b * LSEQ + (LSEQ - 1 - (c * QCH + tau));
            float part = 0.f;
#pragma unroll
            for (int jn = 0; jn < 4; ++jn) {
                const int col = h * 64 + jn * 16 + lm;
                float yv = Y[i][jn][r] + es * Y2[i][jn][r];
                float zv = bf2f(zr[i][r][jn]);
                float gv = yv * silu_f(zv);
                gz[grow * 1024 + col] = f2bf(gv);
                part += gv * gv;
            }
            part += __shfl_xor(part, 1);
            part += __shfl_xor(part, 2);
            part += __shfl_xor(part, 4);
            part += __shfl_xor(part, 8);
            if (lm == 0) atomicAdd(ssq + grow, part);
        }
    }
}

// ---------------------------------------------------------------------------
extern "C" void kernel_launch(void* const* d_in, const int* in_sizes, int n_in,
                              void* d_out, int out_size, void* d_ws, size_t ws_size,
                              hipStream_t stream)
{
    const float* x         = (const float*)d_in[0];
    const float* in_proj_w = (const float*)d_in[1];   // (2192, 512)
    const float* conv_w    = (const float*)d_in[2];   // (1152, 4)
    const float* conv_b    = (const float*)d_in[3];
    const float* dt_bias   = (const float*)d_in[4];   // (16,)
    const float* A_log     = (const float*)d_in[5];
    const float* Dv        = (const float*)d_in[6];
    const float* rms_w     = (const float*)d_in[7];
    const float* out_proj_w= (const float*)d_in[8];   // (512, 1024)
    const float* ln_g      = (const float*)d_in[9];
    const float* ln_b      = (const float*)d_in[10];
    const float* w1        = (const float*)d_in[11];  // (1024, 1024)
    const float* b1        = (const float*)d_in[12];
    const float* w2        = (const float*)d_in[13];  // (512, 1024)
    const float* b2        = (const float*)d_in[14];
    float* out = (float*)d_out;
    char* base = (char*)d_ws;

    // workspace layout (byte offsets), liveness-safe reuse:
    ushort* g1out = (ushort*)(base);                   // [T,2304] bf16   75.5 MB
    ushort* xh_b  = (ushort*)(base + 75497472);        // [T,1024] bf16   33.5 MB
    ushort* bc_b  = (ushort*)(base + 109051904);       // [T,128]  bf16    4.2 MB
    ushort* gz    = (ushort*)(base + 113246208);       // [T,1024] bf16   33.5 MB
    ushort* xbf   = (ushort*)(base + 113246208);       // [T,512] bf16 (dead before gz)
    float*  dtr   = (float*) (base + 146800640);       // [64][4096]       1 MB
    float*  segb  = (float*) (base + 148897792);       // [64][4096]       1 MB
    float*  alphab= (float*) (base + 149946368);       // [64][4096]       1 MB
    ushort* wip   = (ushort*)(base + 150994944);       // [2304,512] bf16
    ushort* w1g   = (ushort*)(base + 153354240);       // [1024,512] bf16 (ln_g folded)
    ushort* wopb  = (ushort*)(base + 154402816);       // [512,1024] bf16
    ushort* w2b   = (ushort*)(base + 155451392);       // [512,1024] bf16
    float*  Pbuf  = (float*) (base + 156499968);       // [2048]
    float*  ssqp  = (float*) (base + 156508160);       // [16384] rms ssq accum
    // LN stats live inside dtr's 1MB region (dtr dead after ssd_y):
    float*  invv = dtr;                                // [16384]
    float*  miv  = dtr + 16384;                        // [16384]
    // Sg/SB reuse wip (dead after in_proj; prep_rowsums runs after it).
    float*  Sg   = (float*)wip;
    float*  SB   = (float*)wip + 1024;
    // post-scan reuse:
    ushort* y2bf = (ushort*)(base + 33554432);         // [T,512] bf16 (g1out dead)
    ushort* h1  = gz;                                  // [T,1024] bf16 (gz dead after out_proj)
    // chunk states: 64 tiles/seq-head x 4096 f32 == out_size; d_out dead until MLP2
    float* sbuf = out;

    // ---- casts / weight prep ----
    cast_x_k<<<(TTOK * 512 / 4 + 255) / 256, 256, 0, stream>>>(
        (const float4*)x, (ushort4*)xbf, TTOK * 512 / 4);
    prep_weights<<<((NPAD * 512 + 1024 * 512 + 2 * 512 * 1024) / 4 + 255) / 256, 256, 0, stream>>>(
        in_proj_w, w1, out_proj_w, w2, rms_w, ln_g, wip, w1g, wopb, w2b);

    // ---- in_proj ----  (1-D grid, XCD swizzle inside; BK=64, round-7 config)
    gemm256<0, ushort, 256><<<dim3((NPAD / 256) * (TTOK / 256)), 512, 0, stream>>>(
        xbf, wip, nullptr, nullptr, nullptr, nullptr, g1out, TTOK, NPAD, 512);

    // Sg/SB for the LN->MLP1 fold (wip region is dead from here on)
    prep_rowsums<<<256, 256, 0, stream>>>(w1, ln_g, ln_b, b1, Sg, SB);

    seg_scan<<<dim3(NCH, 16, 4), 128, 0, stream>>>(g1out, dt_bias, A_log, dtr, segb, alphab, Pbuf);
    conv_silu<<<((TTOK / CSTRIP) * 144 + 255) / 256, 256, 0, stream>>>(
        g1out, conv_w, conv_b, xh_b, bc_b);

    // ---- SSD chunked scan ----
    ssd_states  <<<dim3(NCH, 16, 4), 256, 0, stream>>>(xh_b, bc_b, alphab, sbuf);
    scan_combine<<<dim3(4, 16, 4),   256, 0, stream>>>(sbuf, Pbuf, ssqp);
    ssd_y       <<<dim3(NCH, 16, 4), 256, 0, stream>>>(xh_b, bc_b, segb, dtr, Dv,
                                                       sbuf, g1out, gz, ssqp);

    // ---- projections + MLP (rms fused into out_proj; LN folded into MLP1) ----
    gemm256<2, ushort, 128><<<dim3((512 / 128) * (TTOK / 256)), 512, 0, stream>>>(
        gz, wopb, nullptr, ssqp, nullptr, nullptr, y2bf, TTOK, 512, 1024);
    ln_stats<<<TTOK / 16, 256, 0, stream>>>(y2bf, miv, invv);
    gemm256<5, ushort, 256><<<dim3((1024 / 256) * (TTOK / 256)), 512, 0, stream>>>(
        y2bf, w1g, SB, miv, invv, Sg, h1, TTOK, 1024, 512);
    gemm256<0, float, 128><<<dim3((512 / 128) * (TTOK / 256)), 512, 0, stream>>>(
        h1, w2b, b2, nullptr, nullptr, nullptr, out, TTOK, 512, 1024);
}

// Round 10
// 388.497 us; speedup vs baseline: 1.0414x; 1.0143x over previous
//
#include <hip/hip_runtime.h>
#include <cstddef>
#include <cstdint>
#include <math.h>

// Problem constants
#define LSEQ   4096
#define BATCH  4
#define TTOK   (LSEQ * BATCH)      // 16384 rows
#define QCH    128                 // scan chunk length
#define NCH    (LSEQ / QCH)        // 32 chunks per sequence
#define NPAD   2304                // in_proj N padded to 18*128
// D_MODEL=512, D_INNER=1024, CONV_DIM=1152, NHEADS=16, HEADDIM=64, D_STATE=64
// g1out layout (ld 2304): [0,1024) z | [1024,2176) xBC | [2176,2192) dt_raw | pad
// Scan runs in reversed-time index r = 4095 - l (forward scan in r).
// rms scale KEPT (rounds 4-6: LN-invariance fails for tiny-norm rows).
// LN folded into MLP1 (exact algebra), stats from dedicated ln_stats kernel.
// in_proj split into 2 launches to kill round quantization (576 blocks = 2.25
// rounds -> 3 lockstep rounds): cols [0,2048) BN=256 grid 512 (exactly 2
// rounds) + cols [2048,2304) BN=128 grid 128 (1 round, small-tile T_block).

typedef __attribute__((ext_vector_type(8))) short short8;
typedef __attribute__((ext_vector_type(8))) unsigned short ushortx8;
typedef __attribute__((ext_vector_type(4))) float floatx4;

// ---- bf16 helpers (manual, RNE) ----
__device__ __forceinline__ float bf2f(ushort u) {
    union { unsigned int i; float f; } v; v.i = ((unsigned int)u) << 16; return v.f;
}
__device__ __forceinline__ ushort f2bf(float f) {
    union { float f; unsigned int i; } v; v.f = f;
    unsigned int r = v.i + 0x7fffu + ((v.i >> 16) & 1u);
    return (ushort)(r >> 16);
}
__device__ __forceinline__ float silu_f(float a) {
    return a / (1.f + __expf(-a));
}

__device__ __forceinline__ void storev(float* p, float v)  { *p = v; }
__device__ __forceinline__ void storev(ushort* p, float v) { *p = f2bf(v); }

// 16B-chunk XOR swizzles for LDS tiles (conflict-free b128 frag reads)
__device__ __forceinline__ int sw64i(int row, int col) {
    return row * 64 + ((((col >> 3) ^ row) & 7) << 3) + (col & 7);
}
__device__ __forceinline__ int sw128i(int row, int col) {
    return row * 128 + ((((col >> 3) ^ row) & 15) << 3) + (col & 7);
}

// async 16B global -> LDS (wave-uniform LDS base + lane*16)
__device__ __forceinline__ void gload_lds16(const ushort* g, short* l) {
    __builtin_amdgcn_global_load_lds(
        (const __attribute__((address_space(1))) void*)g,
        (__attribute__((address_space(3))) void*)l, 16, 0, 0);
}

// raw waits / barriers (NO __syncthreads in the GEMM: it would drain vmcnt)
__device__ __forceinline__ void vmwait4() { asm volatile("s_waitcnt vmcnt(4)" ::: "memory"); }
__device__ __forceinline__ void vmwait3() { asm volatile("s_waitcnt vmcnt(3)" ::: "memory"); }
__device__ __forceinline__ void vmwait0() { asm volatile("s_waitcnt vmcnt(0)" ::: "memory"); }
__device__ __forceinline__ void wgbar() {
    __builtin_amdgcn_sched_barrier(0);
    __builtin_amdgcn_s_barrier();
    __builtin_amdgcn_sched_barrier(0);
}

// ---------------------------------------------------------------------------
// 256x{256,128} 8-phase bf16 MFMA GEMM: C[M,N] = epi(A[M,K] @ W[N,K]^T + bias)
// N = tile-space width (grid decode), ldc = C row stride (differs for the
// offset in_proj tail sub-GEMM).
// EPI: 0 none | 1 silu
//      2 rms row-scale: v *= rsqrt(aux[row]/1024 + eps)
//      5 fused-LayerNorm affine + silu:
//        v = silu(acc*inv - mi*aux3[col] + bias[col]); mi=aux[row], inv=aux2[row]
// ---------------------------------------------------------------------------
template<int EPI, typename OutT, int BN>
__global__ __launch_bounds__(512, 2)
void gemm256(const ushort* __restrict__ A, const ushort* __restrict__ W,
             const float* __restrict__ bias, const float* __restrict__ aux,
             const float* __restrict__ aux2, const float* __restrict__ aux3,
             OutT* __restrict__ C, int M, int N, int ldc, int K)
{
    constexpr int BHALF = (BN == 256) ? 8192 : 4096;  // shorts per B half-region
    constexpr int BLD   = (BN == 256) ? 2 : 1;        // gloads/thread per B half
    constexpr int NFH   = (BN == 256) ? 2 : 1;        // B frags per N-half per wave
    __shared__ __align__(16) short As[4 * 8192];      // 2 buf x 2 half x [128][64]
    __shared__ __align__(16) short Bs[4 * BHALF];     // 2 buf x 2 half x [BN/2][64]

    const int tid = threadIdx.x;
    const int w = tid >> 6, lane = tid & 63;
    const int lm = lane & 15, quad = lane >> 4;
    const int wm = w & 1, wn = w >> 1;

    // XCD-chunked bijective swizzle (nwg % 8 == 0 for all our grids)
    const int nwg = gridDim.x;
    const int chunk = nwg >> 3;
    const int bid = blockIdx.x;
    const int vid = (bid & 7) * chunk + (bid >> 3);
    const int NX = N / BN;
    const int bx = vid % NX, by = vid / NX;
    const int m0 = by * 256, n0 = bx * BN;
    const int NT = K >> 6;                            // K-tiles (>= 8 here)

    const int srow = tid >> 3;
    const int scol = ((tid & 7) ^ (srow & 7)) * 8;
    const ushort* ga = A + (size_t)(m0 + srow) * K + scol;
    const ushort* gb = W + (size_t)(n0 + srow) * K + scol;
    short* lA = As + w * 512;
    short* lB = Bs + w * 512;

    auto STAGE_A = [&](int bf, int h, int kt) {
        const ushort* g = ga + (size_t)(h * 128) * K + kt * 64;
        short* l = lA + bf * 16384 + h * 8192;
        gload_lds16(g, l);
        gload_lds16(g + (size_t)64 * K, l + 4096);
    };
    auto STAGE_B = [&](int bf, int h, int kt) {
        const ushort* g = gb + (size_t)(h * (BN / 2)) * K + kt * 64;
        short* l = lB + bf * 2 * BHALF + h * BHALF;
        gload_lds16(g, l);
        if constexpr (BLD == 2) gload_lds16(g + (size_t)64 * K, l + 4096);
    };

    int aRow[4], bRow[NFH], kch[2];
#pragma unroll
    for (int i = 0; i < 4; ++i) aRow[i] = ((i * 2 + wm) * 16 + lm) * 64;
#pragma unroll
    for (int j = 0; j < NFH; ++j) bRow[j] = ((j * 4 + wn) * 16 + lm) * 64;
#pragma unroll
    for (int ks = 0; ks < 2; ++ks) kch[ks] = (((ks * 4 + quad) ^ (lm & 7)) * 8);

    floatx4 acc[8][2 * NFH];
#pragma unroll
    for (int i = 0; i < 8; ++i)
#pragma unroll
        for (int j = 0; j < 2 * NFH; ++j) acc[i][j] = (floatx4){0.f, 0.f, 0.f, 0.f};
    short8 af[4][2], bfr[NFH][2];

#define G_LOADA(bfv, MH)                                                      \
    {                                                                         \
        const short* _ba = As + (bfv) * 16384 + (MH) * 8192;                  \
        _Pragma("unroll")                                                     \
        for (int _i = 0; _i < 4; ++_i)                                        \
            _Pragma("unroll")                                                 \
            for (int _k = 0; _k < 2; ++_k)                                    \
                af[_i][_k] = *(const short8*)(_ba + aRow[_i] + kch[_k]);      \
    }
#define G_LOADB(bfv, NH)                                                      \
    {                                                                         \
        const short* _bb = Bs + (bfv) * 2 * BHALF + (NH) * BHALF;             \
        _Pragma("unroll")                                                     \
        for (int _j = 0; _j < NFH; ++_j)                                      \
            _Pragma("unroll")                                                 \
            for (int _k = 0; _k < 2; ++_k)                                    \
                bfr[_j][_k] = *(const short8*)(_bb + bRow[_j] + kch[_k]);     \
    }
#define G_MMA(MH, NH)                                                         \
    {                                                                         \
        __builtin_amdgcn_s_setprio(1);                                        \
        _Pragma("unroll")                                                     \
        for (int _i = 0; _i < 4; ++_i)                                        \
            _Pragma("unroll")                                                 \
            for (int _j = 0; _j < NFH; ++_j)                                  \
                _Pragma("unroll")                                             \
                for (int _k = 0; _k < 2; ++_k)                                \
                    acc[(MH) * 4 + _i][(NH) * NFH + _j] =                     \
                        __builtin_amdgcn_mfma_f32_16x16x32_bf16(              \
                            af[_i][_k], bfr[_j][_k],                          \
                            acc[(MH) * 4 + _i][(NH) * NFH + _j], 0, 0, 0);    \
        __builtin_amdgcn_s_setprio(0);                                        \
    }

    STAGE_A(0, 0, 0); STAGE_B(0, 0, 0); STAGE_B(0, 1, 0); STAGE_A(0, 1, 0);
    STAGE_A(1, 0, 1); STAGE_B(1, 1, 1);
    if constexpr (BLD == 2) vmwait4(); else vmwait3();
    wgbar();

    for (int t = 0; t < NT; ++t) {
        const int bf = t & 1;
        G_LOADA(bf, 0); G_LOADB(bf, 0);
        if (t + 1 < NT) STAGE_B(bf ^ 1, 0, t + 1);
        wgbar();
        G_MMA(0, 0);
        wgbar();
        G_LOADB(bf, 1);
        if (t + 1 < NT) STAGE_A(bf ^ 1, 1, t + 1);
        wgbar();
        G_MMA(0, 1);
        wgbar();
        G_LOADA(bf, 1);
        if (t + 2 < NT) STAGE_A(bf, 0, t + 2);
        wgbar();
        G_MMA(1, 1);
        wgbar();
        G_LOADB(bf, 0);
        if (t + 2 < NT) STAGE_B(bf, 1, t + 2);
        wgbar();
        G_MMA(1, 0);
        __builtin_amdgcn_sched_barrier(0);
        if (t + 2 < NT) { if constexpr (BLD == 2) vmwait4(); else vmwait3(); }
        else if (t + 1 < NT) vmwait0();
        wgbar();
    }
#undef G_LOADA
#undef G_LOADB
#undef G_MMA

    // epilogue
#pragma unroll
    for (int ii = 0; ii < 8; ++ii) {
        const int rb = m0 + (ii * 2 + wm) * 16 + quad * 4;
#pragma unroll
        for (int rr = 0; rr < 4; ++rr) {
            const int row = rb + rr;
            float inv = 1.f, mi = 0.f, scale = 1.f;
            if (EPI == 2) scale = rsqrtf(aux[row] * (1.f / 1024.f) + 1e-5f);
            if (EPI == 5) { mi = aux[row]; inv = aux2[row]; }
#pragma unroll
            for (int jj = 0; jj < 2 * NFH; ++jj) {
                const int col = n0 + (jj * 4 + wn) * 16 + lm;
                float v = acc[ii][jj][rr];
                if (EPI == 5) {
                    v = silu_f(v * inv - mi * aux3[col] + bias[col]);
                } else {
                    if (bias) v += bias[col];
                    if (EPI == 1) v = silu_f(v);
                    if (EPI == 2) v *= scale;
                }
                storev(&C[(size_t)row * ldc + col], v);
            }
        }
    }
}

// ---------------------------------------------------------------------------
// fused prep: x cast (f32->bf16), in_proj pad, w1 fold (+ln_g), wop*rms, w2
// ---------------------------------------------------------------------------
#define XCAST (TTOK * 512)
__global__ __launch_bounds__(256)
void prep_all(const float* __restrict__ x, const float* __restrict__ ipw,
              const float* __restrict__ w1, const float* __restrict__ wop,
              const float* __restrict__ w2, const float* __restrict__ rw,
              const float* __restrict__ lng,
              ushort* __restrict__ xbf, ushort* __restrict__ wip,
              ushort* __restrict__ w1g, ushort* __restrict__ wopb,
              ushort* __restrict__ w2b)
{
    int i4 = (blockIdx.x * 256 + threadIdx.x) * 4;
    if (i4 < XCAST) {
        float4 s = *(const float4*)(x + (size_t)i4);
        ushort4 v;
        v.x = f2bf(s.x); v.y = f2bf(s.y); v.z = f2bf(s.z); v.w = f2bf(s.w);
        *(ushort4*)(xbf + i4) = v;
        return;
    }
    i4 -= XCAST;
    if (i4 < NPAD * 512) {
        int row = i4 >> 9;
        ushort4 v;
        if (row < 2192) {
            float4 s = *(const float4*)(ipw + (size_t)i4);
            v.x = f2bf(s.x); v.y = f2bf(s.y); v.z = f2bf(s.z); v.w = f2bf(s.w);
        } else { v.x = v.y = v.z = v.w = 0; }
        *(ushort4*)(wip + i4) = v;
        return;
    }
    i4 -= NPAD * 512;
    if (i4 < 1024 * 512) {
        int j = i4 >> 9, d = i4 & 511;
        float4 a = *(const float4*)(w1 + (size_t)j * 1024 + d);
        float4 b = *(const float4*)(w1 + (size_t)j * 1024 + 512 + d);
        float4 g = *(const float4*)(lng + d);
        ushort4 v;
        v.x = f2bf((a.x + b.x) * g.x); v.y = f2bf((a.y + b.y) * g.y);
        v.z = f2bf((a.z + b.z) * g.z); v.w = f2bf((a.w + b.w) * g.w);
        *(ushort4*)(w1g + i4) = v;
        return;
    }
    i4 -= 1024 * 512;
    if (i4 < 512 * 1024) {
        float4 s = *(const float4*)(wop + (size_t)i4);
        float4 g = *(const float4*)(rw + (i4 & 1023));
        ushort4 v;
        v.x = f2bf(s.x * g.x); v.y = f2bf(s.y * g.y);
        v.z = f2bf(s.z * g.z); v.w = f2bf(s.w * g.w);
        *(ushort4*)(wopb + i4) = v;
        return;
    }
    i4 -= 512 * 1024;
    if (i4 < 512 * 1024) {
        float4 s = *(const float4*)(w2 + (size_t)i4);
        ushort4 v;
        v.x = f2bf(s.x); v.y = f2bf(s.y); v.z = f2bf(s.z); v.w = f2bf(s.w);
        *(ushort4*)(w2b + i4) = v;
    }
}

// row-sums for the LN->MLP1 fold: Sg[n] = sum_k w1f[n,k]*ln_g[k],
// SB[n] = sum_k w1f[n,k]*ln_b[k] + b1[n], with w1f = w1[:, :512]+w1[:, 512:].
__global__ __launch_bounds__(256)
void prep_rowsums(const float* __restrict__ w1, const float* __restrict__ g,
                  const float* __restrict__ bb, const float* __restrict__ b1,
                  float* __restrict__ Sg, float* __restrict__ SB)
{
    const int n = blockIdx.x * 4 + (threadIdx.x >> 6);
    const int lane = threadIdx.x & 63;
    float sg = 0.f, sb = 0.f;
#pragma unroll
    for (int it = 0; it < 8; ++it) {
        int k = it * 64 + lane;
        float wv = w1[(size_t)n * 1024 + k] + w1[(size_t)n * 1024 + 512 + k];
        sg += wv * g[k];
        sb += wv * bb[k];
    }
#pragma unroll
    for (int off = 32; off > 0; off >>= 1) {
        sg += __shfl_xor(sg, off);
        sb += __shfl_xor(sb, off);
    }
    if (lane == 0) { Sg[n] = sg; SB[n] = sb + b1[n]; }
}

// ---------------------------------------------------------------------------
// LN row stats from bf16 y2 (already rms-scaled): one wave per row.
// Writes mi = mean*inv and inv = rsqrt(var+eps).
// ---------------------------------------------------------------------------
__global__ __launch_bounds__(256)
void ln_stats(const ushort* __restrict__ y2, float* __restrict__ miv,
              float* __restrict__ invv)
{
    const int w = threadIdx.x >> 6, lane = threadIdx.x & 63;
#pragma unroll
    for (int it = 0; it < 4; ++it) {
        const int row = blockIdx.x * 16 + it * 4 + w;
        ushortx8 v = *(const ushortx8*)(y2 + (size_t)row * 512 + lane * 8);
        float s = 0.f, ss = 0.f;
#pragma unroll
        for (int e = 0; e < 8; ++e) { float f = bf2f(v[e]); s += f; ss += f * f; }
#pragma unroll
        for (int off = 32; off > 0; off >>= 1) {
            s += __shfl_xor(s, off);
            ss += __shfl_xor(ss, off);
        }
        if (lane == 0) {
            float mean = s * (1.f / 512.f);
            float var  = ss * (1.f / 512.f) - mean * mean;
            float inv  = rsqrtf(var + 1e-5f);
            miv[row]  = mean * inv;
            invv[row] = inv;
        }
    }
}

// ---------------------------------------------------------------------------
// seg_scan (dt fused)
// ---------------------------------------------------------------------------
__global__ __launch_bounds__(128)
void seg_scan(const ushort* __restrict__ raw, const float* __restrict__ dt_bias,
              const float* __restrict__ A_log, float* __restrict__ dtr,
              float* __restrict__ segb, float* __restrict__ alphab,
              float* __restrict__ Pb)
{
    __shared__ float s[128];
    const int tid = threadIdx.x;
    const int c = blockIdx.x, h = blockIdx.y, b = blockIdx.z;
    const int bh = b * 16 + h;
    const int r = c * QCH + tid;
    const size_t grow = (size_t)b * LSEQ + (LSEQ - 1 - r);
    const size_t idx = (size_t)bh * LSEQ + r;

    float v = bf2f(raw[grow * NPAD + 2176 + h]) + dt_bias[h];
    float dt = (v > 20.f) ? v : log1pf(expf(v));
    float Ah = -expf(A_log[h]);
    s[tid] = dt * Ah;
    __syncthreads();
#pragma unroll
    for (int off = 1; off < 128; off <<= 1) {
        float t = (tid >= off) ? s[tid - off] : 0.f;
        __syncthreads();
        s[tid] += t;
        __syncthreads();
    }
    float seg = s[tid];
    float last = s[127];
    dtr[idx] = dt;
    segb[idx] = seg;
    alphab[idx] = __expf(last - seg) * dt;
    if (tid == 127) Pb[bh * NCH + c] = __expf(last);
}

// ---------------------------------------------------------------------------
// Anti-causal depthwise conv + silu, rolling-window.
// ---------------------------------------------------------------------------
#define CSTRIP 8
__global__ __launch_bounds__(256)
void conv_silu(const ushort* __restrict__ raw, const float* __restrict__ cw,
               const float* __restrict__ cb, ushort* __restrict__ xh,
               ushort* __restrict__ bc)
{
    const int idx = blockIdx.x * 256 + threadIdx.x;   // over (TTOK/CSTRIP)*144
    if (idx >= (TTOK / CSTRIP) * 144) return;
    const int strip = idx / 144;
    const int g = idx - strip * 144;
    const int c0 = g * 8;
    const int row0 = strip * CSTRIP;                  // global first row
    const int l0 = row0 & (LSEQ - 1);

    float wt[4][8];
    float bias[8];
#pragma unroll
    for (int e = 0; e < 8; ++e) {
        float4 a = *(const float4*)(cw + (c0 + e) * 4);
        wt[0][e] = a.w; wt[1][e] = a.z; wt[2][e] = a.y; wt[3][e] = a.x;
        bias[e] = cb[c0 + e];
    }

    float win[4][8];
    auto loadrow = [&](int l, float* dst) {
        if (l < LSEQ) {
            ushortx8 v = *(const ushortx8*)(raw + (size_t)(row0 - l0 + l) * NPAD + 1024 + c0);
#pragma unroll
            for (int e = 0; e < 8; ++e) dst[e] = bf2f(v[e]);
        } else {
#pragma unroll
            for (int e = 0; e < 8; ++e) dst[e] = 0.f;
        }
    };

    {
        const int ltop = l0 + CSTRIP - 1;
        loadrow(ltop + 1, win[(ltop + 1) & 3]);
        loadrow(ltop + 2, win[(ltop + 2) & 3]);
        loadrow(ltop + 3, win[(ltop + 3) & 3]);
    }
#pragma unroll
    for (int s = CSTRIP - 1; s >= 0; --s) {
        const int l = l0 + s;
        loadrow(l, win[l & 3]);
        ushortx8 o;
#pragma unroll
        for (int e = 0; e < 8; ++e) {
            float acc = bias[e];
#pragma unroll
            for (int j = 0; j < 4; ++j)
                acc = fmaf(wt[j][e], win[(l + j) & 3][e], acc);
            o[e] = f2bf(silu_f(acc));
        }
        const size_t row = (size_t)row0 + s;
        if (c0 < 1024) *(ushortx8*)(xh + row * 1024 + c0) = o;
        else           *(ushortx8*)(bc + row * 128 + (c0 - 1024)) = o;
    }
}

// ---------------------------------------------------------------------------
// SSD pass A: per tile (c,h,b), chunk end-state
// ---------------------------------------------------------------------------
__global__ __launch_bounds__(256)
void ssd_states(const ushort* __restrict__ xh, const ushort* __restrict__ bc,
                const float* __restrict__ alphab, float* __restrict__ sbuf)
{
    __shared__ __align__(16) ushort XT[64 * 128];
    __shared__ __align__(16) ushort BpT[64 * 128];
    const int tid = threadIdx.x;
    const int w = tid >> 6, lane = tid & 63;
    const int lm = lane & 15, quad = lane >> 4;
    const int c = blockIdx.x, h = blockIdx.y, b = blockIdx.z;
    const int bh = b * 16 + h;
    const size_t abase = (size_t)bh * LSEQ + c * QCH;

#pragma unroll
    for (int it = 0; it < 8; ++it) {
        int idx = it * 256 + tid;
        int tau = idx >> 4, e4 = (idx & 15) * 4;
        size_t grow = (size_t)b * LSEQ + (LSEQ - 1 - (c * QCH + tau));
        ushort4 xv = *(const ushort4*)(xh + grow * 1024 + h * 64 + e4);
        XT[sw128i(e4 + 0, tau)] = xv.x;
        XT[sw128i(e4 + 1, tau)] = xv.y;
        XT[sw128i(e4 + 2, tau)] = xv.z;
        XT[sw128i(e4 + 3, tau)] = xv.w;
        float al = alphab[abase + tau];
        ushort4 bv = *(const ushort4*)(bc + grow * 128 + e4);
        BpT[sw128i(e4 + 0, tau)] = f2bf(bf2f(bv.x) * al);
        BpT[sw128i(e4 + 1, tau)] = f2bf(bf2f(bv.y) * al);
        BpT[sw128i(e4 + 2, tau)] = f2bf(bf2f(bv.z) * al);
        BpT[sw128i(e4 + 3, tau)] = f2bf(bf2f(bv.w) * al);
    }
    __syncthreads();

    floatx4 L[4];
#pragma unroll
    for (int j = 0; j < 4; ++j) L[j] = (floatx4){0.f, 0.f, 0.f, 0.f};
#pragma unroll
    for (int kc = 0; kc < 4; ++kc) {
        short8 a = *(const short8*)(XT + sw128i(w * 16 + lm, kc * 32 + quad * 8));
#pragma unroll
        for (int jn = 0; jn < 4; ++jn) {
            short8 bf = *(const short8*)(BpT + sw128i(jn * 16 + lm, kc * 32 + quad * 8));
            L[jn] = __builtin_amdgcn_mfma_f32_16x16x32_bf16(a, bf, L[jn], 0, 0, 0);
        }
    }
    float* Sp = sbuf + ((size_t)bh * NCH + c) * 4096;
#pragma unroll
    for (int jn = 0; jn < 4; ++jn)
#pragma unroll
        for (int r = 0; r < 4; ++r) {
            int p = w * 16 + quad * 4 + r;
            Sp[p * 64 + jn * 16 + lm] = L[jn][r];
        }
}

// ---------------------------------------------------------------------------
// Combine: sequential over chunks in scan (r) order with DEPTH-4 prefetch.
// Writes the chunk-start state h as PACKED BF16 (block-partitioned layout:
// block q writes only ushort [2048q,+1024) = f32 region it reads; the
// per-iteration barrier orders slot-c reads (4 iters earlier) before writes).
// q==0 blocks also zero the per-row ssq accumulator for the rms fusion.
// ---------------------------------------------------------------------------
__global__ __launch_bounds__(256)
void scan_combine(float* __restrict__ sbuf, const float* __restrict__ Pb,
                  float* __restrict__ ssq)
{
    const int tid = threadIdx.x;
    const int q = blockIdx.x, h = blockIdx.y, b = blockIdx.z;
    const int bh = b * 16 + h;
    if (q == 0) ssq[(size_t)bh * 256 + tid] = 0.f;
    const int off = q * 1024 + tid * 4;
    float c0 = 0.f, c1 = 0.f, c2 = 0.f, c3 = 0.f;

    float* slotbase = sbuf + (size_t)bh * NCH * 4096;
    float* sp0 = slotbase + off;
    const float* Pp = Pb + bh * NCH;

    float4 nx[4];
    float Pn[4];
#pragma unroll
    for (int d = 0; d < 4; ++d) {
        nx[d] = *(const float4*)(sp0 + (size_t)d * 4096);
        Pn[d] = Pp[d];
    }
#pragma unroll
    for (int c = 0; c < NCH; ++c) {
        float4 lv = nx[c & 3];
        float P  = Pn[c & 3];
        if (c + 4 < NCH) {
            nx[c & 3] = *(const float4*)(sp0 + (size_t)(c + 4) * 4096);
            Pn[c & 3] = Pp[c + 4];
        }
        __syncthreads();   // slot-c reads (iter c-4) done before slot-c writes
        ushort* hdst = (ushort*)(slotbase + (size_t)c * 4096) + q * 2048 + tid * 4;
        ushort4 hv;
        hv.x = f2bf(c0); hv.y = f2bf(c1); hv.z = f2bf(c2); hv.w = f2bf(c3);
        *(ushort4*)hdst = hv;
        c0 = fmaf(c0, P, lv.x);
        c1 = fmaf(c1, P, lv.y);
        c2 = fmaf(c2, P, lv.z);
        c3 = fmaf(c3, P, lv.w);
    }
}

// ---------------------------------------------------------------------------
// SSD pass C: Y = [M o (C B^T)] X + diag(exp(seg)) C h_start^T, D on diag,
// z-gate fused, writes gated bf16 + atomic per-row ssq (rms fusion).
// Triangular skip with balanced bands.
// ---------------------------------------------------------------------------
__global__ __launch_bounds__(256)
void ssd_y(const ushort* __restrict__ xh, const ushort* __restrict__ bc,
           const float* __restrict__ segb, const float* __restrict__ dtb_,
           const float* __restrict__ Dvec, const float* __restrict__ sbuf,
           const ushort* __restrict__ zb, ushort* __restrict__ gz,
           float* __restrict__ ssq)
{
    __shared__ __align__(16) char smem[66560];
    ushort* Ct  = (ushort*)smem;             // [128][64]  sw64  (C rows tau)
    ushort* XT  = (ushort*)(smem + 16384);   // [64][128]  sw128 (X^T: d, tau)
    ushort* Bt  = (ushort*)(smem + 32768);   // [128][64]  sw64  (dead after GEMM1)
    ushort* Wl  = (ushort*)(smem + 32768);   // [128][128] sw128 (overlaps Bt)
    float* segl = (float*)(smem + 65536);    // [128]
    float* dtl  = (float*)(smem + 66048);    // [128]

    const int tid = threadIdx.x;
    const int w = tid >> 6, lane = tid & 63;
    const int lm = lane & 15, quad = lane >> 4;
    const int c = blockIdx.x, h = blockIdx.y, b = blockIdx.z;
    const int bh = b * 16 + h;
    const size_t abase = (size_t)bh * LSEQ + c * QCH;
    int band[2]; band[0] = w; band[1] = 7 - w;

    if (tid < 128) {
        segl[tid] = segb[abase + tid];
        dtl[tid]  = dtb_[abase + tid];
    }
#pragma unroll
    for (int it = 0; it < 8; ++it) {
        int idx = it * 256 + tid;
        int tau = idx >> 4, e4 = (idx & 15) * 4;
        size_t grow = (size_t)b * LSEQ + (LSEQ - 1 - (c * QCH + tau));
        ushort4 bv = *(const ushort4*)(bc + grow * 128 + e4);
        ushort4 cv = *(const ushort4*)(bc + grow * 128 + 64 + e4);
        *(ushort4*)(Bt + sw64i(tau, e4)) = bv;
        *(ushort4*)(Ct + sw64i(tau, e4)) = cv;
        ushort4 xv = *(const ushort4*)(xh + grow * 1024 + h * 64 + e4);
        XT[sw128i(e4 + 0, tau)] = xv.x;
        XT[sw128i(e4 + 1, tau)] = xv.y;
        XT[sw128i(e4 + 2, tau)] = xv.z;
        XT[sw128i(e4 + 3, tau)] = xv.w;
    }
    // prefetch z-gate values into registers (latency hidden under GEMM1/W-gen)
    ushort zr[2][4][4];
#pragma unroll
    for (int i = 0; i < 2; ++i)
#pragma unroll
        for (int r = 0; r < 4; ++r) {
            const int tau = band[i] * 16 + quad * 4 + r;
            const size_t grow = (size_t)b * LSEQ + (LSEQ - 1 - (c * QCH + tau));
#pragma unroll
            for (int jn = 0; jn < 4; ++jn)
                zr[i][r][jn] = zb[grow * NPAD + h * 64 + jn * 16 + lm];
        }
    __syncthreads();

    // GEMM1: G = C . B^T over n; only jn-blocks <= band
    floatx4 G[2][8];
#pragma unroll
    for (int i = 0; i < 2; ++i)
#pragma unroll
        for (int j = 0; j < 8; ++j) G[i][j] = (floatx4){0.f, 0.f, 0.f, 0.f};
#pragma unroll
    for (int i = 0; i < 2; ++i) {
        const int bnd = band[i];
        short8 a0 = *(const short8*)(Ct + sw64i(bnd * 16 + lm, 0 * 32 + quad * 8));
        short8 a1 = *(const short8*)(Ct + sw64i(bnd * 16 + lm, 1 * 32 + quad * 8));
#pragma unroll
        for (int jn = 0; jn < 8; ++jn) {
            if (jn <= bnd) {
                short8 b0 = *(const short8*)(Bt + sw64i(jn * 16 + lm, 0 * 32 + quad * 8));
                short8 b1 = *(const short8*)(Bt + sw64i(jn * 16 + lm, 1 * 32 + quad * 8));
                G[i][jn] = __builtin_amdgcn_mfma_f32_16x16x32_bf16(a0, b0, G[i][jn], 0, 0, 0);
                G[i][jn] = __builtin_amdgcn_mfma_f32_16x16x32_bf16(a1, b1, G[i][jn], 0, 0, 0);
            }
        }
    }
    __syncthreads();   // everyone done reading Bt before Wl overwrites it

    const float Dh = Dvec[h];
#pragma unroll
    for (int i = 0; i < 2; ++i) {
        const int bnd = band[i];
        const int taub = bnd * 16;
#pragma unroll
        for (int jn = 0; jn < 8; ++jn) {
            const int sigma = jn * 16 + lm;
            if (jn < bnd) {              // all sigma < all tau
                const float dts = dtl[sigma];
                const float segs = segl[sigma];
#pragma unroll
                for (int r = 0; r < 4; ++r) {
                    const int tau = taub + quad * 4 + r;
                    float wv = dts * G[i][jn][r] * __expf(segl[tau] - segs);
                    Wl[sw128i(tau, sigma)] = f2bf(wv);
                }
            } else if (jn == bnd) {      // diagonal block
                const float dts = dtl[sigma];
                const float segs = segl[sigma];
#pragma unroll
                for (int r = 0; r < 4; ++r) {
                    const int tau = taub + quad * 4 + r;
                    float g = G[i][jn][r];
                    float wv;
                    if (sigma < tau)       wv = dts * g * __expf(segl[tau] - segs);
                    else if (sigma == tau) wv = dts * g + Dh;
                    else                   wv = 0.f;
                    Wl[sw128i(tau, sigma)] = f2bf(wv);
                }
            } else if (jn == bnd + 1 && (bnd & 1) == 0) {  // zero-fill read block
#pragma unroll
                for (int r = 0; r < 4; ++r)
                    Wl[sw128i(taub + quad * 4 + r, sigma)] = 0;
            }
        }
    }
    // no barrier needed: each wave reads back only its own W rows

    // GEMM2: Y = W.X (kc-blocks <= band/2 only); Y2 = C.h^T (separate acc)
    floatx4 Y[2][4], Y2[2][4];
#pragma unroll
    for (int i = 0; i < 2; ++i)
#pragma unroll
        for (int j = 0; j < 4; ++j) {
            Y[i][j]  = (floatx4){0.f, 0.f, 0.f, 0.f};
            Y2[i][j] = (floatx4){0.f, 0.f, 0.f, 0.f};
        }
#pragma unroll
    for (int kc = 0; kc < 4; ++kc) {
        short8 bfx[4];
#pragma unroll
        for (int jn = 0; jn < 4; ++jn)
            bfx[jn] = *(const short8*)(XT + sw128i(jn * 16 + lm, kc * 32 + quad * 8));
#pragma unroll
        for (int i = 0; i < 2; ++i) {
            if (kc <= (band[i] >> 1)) {
                short8 a = *(const short8*)(Wl + sw128i(band[i] * 16 + lm, kc * 32 + quad * 8));
#pragma unroll
                for (int jn = 0; jn < 4; ++jn)
                    Y[i][jn] = __builtin_amdgcn_mfma_f32_16x16x32_bf16(a, bfx[jn], Y[i][jn], 0, 0, 0);
            }
        }
    }
    // H-part: bf16 h from scan_combine, partitioned layout:
    // element (p,n) at ushort offset 2048*(p>>4) + (p&15)*64 + n
    const ushort* hb = (const ushort*)(sbuf + ((size_t)bh * NCH + c) * 4096);
#pragma unroll
    for (int kc = 0; kc < 2; ++kc) {
        short8 a2[2];
#pragma unroll
        for (int i = 0; i < 2; ++i)
            a2[i] = *(const short8*)(Ct + sw64i(band[i] * 16 + lm, kc * 32 + quad * 8));
#pragma unroll
        for (int jn = 0; jn < 4; ++jn) {
            short8 bfh = *(const short8*)(hb + jn * 2048 + lm * 64 + kc * 32 + quad * 8);
#pragma unroll
            for (int i = 0; i < 2; ++i)
                Y2[i][jn] = __builtin_amdgcn_mfma_f32_16x16x32_bf16(a2[i], bfh, Y2[i][jn], 0, 0, 0);
        }
    }

    // epilogue: Y + exp(seg)*Y2, z-gate, store bf16, per-row sum of squares
#pragma unroll
    for (int i = 0; i < 2; ++i) {
#pragma unroll
        for (int r = 0; r < 4; ++r) {
            const int tau = band[i] * 16 + quad * 4 + r;
            const float es = __expf(segl[tau]);
            const size_t grow = (size_t)b * LSEQ + (LSEQ - 1 - (c * QCH + tau));
            float part = 0.f;
#pragma unroll
            for (int jn = 0; jn < 4; ++jn) {
                const int col = h * 64 + jn * 16 + lm;
                float yv = Y[i][jn][r] + es * Y2[i][jn][r];
                float zv = bf2f(zr[i][r][jn]);
                float gv = yv * silu_f(zv);
                gz[grow * 1024 + col] = f2bf(gv);
                part += gv * gv;
            }
            part += __shfl_xor(part, 1);
            part += __shfl_xor(part, 2);
            part += __shfl_xor(part, 4);
            part += __shfl_xor(part, 8);
            if (lm == 0) atomicAdd(ssq + grow, part);
        }
    }
}

// ---------------------------------------------------------------------------
extern "C" void kernel_launch(void* const* d_in, const int* in_sizes, int n_in,
                              void* d_out, int out_size, void* d_ws, size_t ws_size,
                              hipStream_t stream)
{
    const float* x         = (const float*)d_in[0];
    const float* in_proj_w = (const float*)d_in[1];   // (2192, 512)
    const float* conv_w    = (const float*)d_in[2];   // (1152, 4)
    const float* conv_b    = (const float*)d_in[3];
    const float* dt_bias   = (const float*)d_in[4];   // (16,)
    const float* A_log     = (const float*)d_in[5];
    const float* Dv        = (const float*)d_in[6];
    const float* rms_w     = (const float*)d_in[7];
    const float* out_proj_w= (const float*)d_in[8];   // (512, 1024)
    const float* ln_g      = (const float*)d_in[9];
    const float* ln_b      = (const float*)d_in[10];
    const float* w1        = (const float*)d_in[11];  // (1024, 1024)
    const float* b1        = (const float*)d_in[12];
    const float* w2        = (const float*)d_in[13];  // (512, 1024)
    const float* b2        = (const float*)d_in[14];
    float* out = (float*)d_out;
    char* base = (char*)d_ws;

    // workspace layout (byte offsets), liveness-safe reuse:
    ushort* g1out = (ushort*)(base);                   // [T,2304] bf16   75.5 MB
    ushort* xh_b  = (ushort*)(base + 75497472);        // [T,1024] bf16   33.5 MB
    ushort* bc_b  = (ushort*)(base + 109051904);       // [T,128]  bf16    4.2 MB
    ushort* gz    = (ushort*)(base + 113246208);       // [T,1024] bf16   33.5 MB
    ushort* xbf   = (ushort*)(base + 113246208);       // [T,512] bf16 (dead before gz)
    float*  dtr   = (float*) (base + 146800640);       // [64][4096]       1 MB
    float*  segb  = (float*) (base + 148897792);       // [64][4096]       1 MB
    float*  alphab= (float*) (base + 149946368);       // [64][4096]       1 MB
    ushort* wip   = (ushort*)(base + 150994944);       // [2304,512] bf16
    ushort* w1g   = (ushort*)(base + 153354240);       // [1024,512] bf16 (ln_g folded)
    ushort* wopb  = (ushort*)(base + 154402816);       // [512,1024] bf16
    ushort* w2b   = (ushort*)(base + 155451392);       // [512,1024] bf16
    float*  Pbuf  = (float*) (base + 156499968);       // [2048]
    float*  ssqp  = (float*) (base + 156508160);       // [16384] rms ssq accum
    // LN stats live inside dtr's 1MB region (dtr dead after ssd_y):
    float*  invv = dtr;                                // [16384]
    float*  miv  = dtr + 16384;                        // [16384]
    // Sg/SB reuse wip (dead after in_proj; prep_rowsums runs after it).
    float*  Sg   = (float*)wip;
    float*  SB   = (float*)wip + 1024;
    // post-scan reuse:
    ushort* y2bf = (ushort*)(base + 33554432);         // [T,512] bf16 (g1out dead)
    ushort* h1  = gz;                                  // [T,1024] bf16 (gz dead after out_proj)
    // chunk states: 64 tiles/seq-head x 4096 f32 == out_size; d_out dead until MLP2
    float* sbuf = out;

    // ---- fused cast + weight prep (one launch) ----
    prep_all<<<(XCAST + NPAD * 512 + 1024 * 512 + 2 * 512 * 1024) / 4 / 256, 256, 0, stream>>>(
        x, in_proj_w, w1, out_proj_w, w2, rms_w, ln_g, xbf, wip, w1g, wopb, w2b);

    // ---- in_proj split: cols [0,2048) at BN=256 (512 blocks = 2 exact
    // rounds) + cols [2048,2304) at BN=128 (128 blocks, small-tile tail) ----
    gemm256<0, ushort, 256><<<dim3((2048 / 256) * (TTOK / 256)), 512, 0, stream>>>(
        xbf, wip, nullptr, nullptr, nullptr, nullptr, g1out, TTOK, 2048, NPAD, 512);
    gemm256<0, ushort, 128><<<dim3((256 / 128) * (TTOK / 256)), 512, 0, stream>>>(
        xbf, wip + (size_t)2048 * 512, nullptr, nullptr, nullptr, nullptr,
        g1out + 2048, TTOK, 256, NPAD, 512);

    // Sg/SB for the LN->MLP1 fold (wip region is dead from here on)
    prep_rowsums<<<256, 256, 0, stream>>>(w1, ln_g, ln_b, b1, Sg, SB);

    seg_scan<<<dim3(NCH, 16, 4), 128, 0, stream>>>(g1out, dt_bias, A_log, dtr, segb, alphab, Pbuf);
    conv_silu<<<((TTOK / CSTRIP) * 144 + 255) / 256, 256, 0, stream>>>(
        g1out, conv_w, conv_b, xh_b, bc_b);

    // ---- SSD chunked scan ----
    ssd_states  <<<dim3(NCH, 16, 4), 256, 0, stream>>>(xh_b, bc_b, alphab, sbuf);
    scan_combine<<<dim3(4, 16, 4),   256, 0, stream>>>(sbuf, Pbuf, ssqp);
    ssd_y       <<<dim3(NCH, 16, 4), 256, 0, stream>>>(xh_b, bc_b, segb, dtr, Dv,
                                                       sbuf, g1out, gz, ssqp);

    // ---- projections + MLP (rms fused into out_proj; LN folded into MLP1) ----
    gemm256<2, ushort, 128><<<dim3((512 / 128) * (TTOK / 256)), 512, 0, stream>>>(
        gz, wopb, nullptr, ssqp, nullptr, nullptr, y2bf, TTOK, 512, 512, 1024);
    ln_stats<<<TTOK / 16, 256, 0, stream>>>(y2bf, miv, invv);
    gemm256<5, ushort, 256><<<dim3((1024 / 256) * (TTOK / 256)), 512, 0, stream>>>(
        y2bf, w1g, SB, miv, invv, Sg, h1, TTOK, 1024, 1024, 512);
    gemm256<0, float, 128><<<dim3((512 / 128) * (TTOK / 256)), 512, 0, stream>>>(
        h1, w2b, b2, nullptr, nullptr, nullptr, out, TTOK, 512, 512, 1024);
}